// Round 5
// baseline (388.702 us; speedup 1.0000x reference)
//
#include <hip/hip_runtime.h>

// PerformerAttnBlock — Round 9: fragment-layout LDS (zero-conflict GEMM).
// LDS stores A/B tiles pre-permuted into the MFMA fragment register layout:
// slot [unit][lane]*16B holds consumer-lane's fragment, staged via per-lane
// pre-permuted GLOBAL source addresses (gload_lds dest stays linear, m173).
// All ds_read_b128 are lane-linear => 0 bank conflicts (round 8 was 8-way
// conflicted: 7.86M conflicts, MfmaUtil 30%). 48KB LDS -> 3 blocks/CU.
// B=4, IN=512, T=4096, EMBED=1024, H=16, D=64, F=256.
// WS (bytes):
//   0         QKVb bf16 [16384][3072] (96MB)
//   100663296 attnb bf16 [16384][1024] (32MB)  -- Abuf bf16 [16384][512] aliases pre-gemm1
//   134217728 Btqkv bf16 [3072][512] (3MB)
//   137363456 WoT bf16 [1024][1024] (2MB)
//   139460608 projb bf16 [256][64] (32KB)
//   139493376 KVg fp32 [64][256][64] (4MB)
//   143687680 Ksumg fp32 [64][256] (64KB)
//   143753216 KVTb bf16 [64][64][256] (2MB)

constexpr int kB  = 4;
constexpr int kIn = 512;
constexpr int kT  = 4096;
constexpr int kE  = 1024;
constexpr int kH  = 16;
constexpr int kD  = 64;
constexpr int kF  = 256;
constexpr int kQKVs = 3072;

typedef __attribute__((ext_vector_type(8))) short bf16x8;
typedef __attribute__((ext_vector_type(4))) float f32x4;

__device__ __forceinline__ unsigned short f2bf(float f) {
    unsigned u = __float_as_uint(f);
    u += 0x7fff + ((u >> 16) & 1);          // RNE
    return (unsigned short)(u >> 16);
}
__device__ __forceinline__ float bf2f(unsigned short s) {
    return __uint_as_float(((unsigned)s) << 16);
}
__device__ __forceinline__ void gload_lds16(const void* g, void* l) {
    __builtin_amdgcn_global_load_lds((const __attribute__((address_space(1))) void*)g,
                                     (__attribute__((address_space(3))) void*)l, 16, 0, 0);
}

// ---------------------------------------------------------------- zero
__global__ __launch_bounds__(256) void zero_kernel(float* __restrict__ p, int n) {
    int i = blockIdx.x * 256 + threadIdx.x;
    if (i < n) p[i] = 0.f;
}

// ---------------------------------------------------------------- copy x -> out[:, :512, :]
__global__ __launch_bounds__(256) void copy_x_kernel(const float* __restrict__ x,
                                                     float* __restrict__ out) {
    const int perB4 = kIn * kT / 4;
    int idx = blockIdx.x * 256 + threadIdx.x;
    if (idx < kB * perB4) {
        int b = idx / perB4, e = idx % perB4;
        ((float4*)out)[(size_t)b * ((kIn + kE) * kT / 4) + e] = ((const float4*)x)[idx];
    }
}

// ---------------------------------------------------------------- flat fp32->bf16
__global__ __launch_bounds__(256) void f2b_flat_kernel(const float* __restrict__ s,
                                                       unsigned short* __restrict__ d, int n4) {
    int i = blockIdx.x * 256 + threadIdx.x;
    if (i < n4) {
        float4 v = ((const float4*)s)[i];
        ushort4 o;
        o.x = f2bf(v.x); o.y = f2bf(v.y); o.z = f2bf(v.z); o.w = f2bf(v.w);
        ((ushort4*)d)[i] = o;
    }
}

// ---------------------------------------------------------------- transpose + fp32->bf16
// src [R][C] fp32 (+z*sstride), dst [C][R] bf16 (+z*dstride)
__global__ __launch_bounds__(256) void trans_f2b_kernel(const float* __restrict__ src,
                                                        unsigned short* __restrict__ dst,
                                                        int R, int C,
                                                        long sstride, long dstride) {
    __shared__ float L[64][68];
    src += (size_t)blockIdx.z * sstride;
    dst += (size_t)blockIdx.z * dstride;
    const int c0 = blockIdx.x * 64, r0 = blockIdx.y * 64;
    const int tid = threadIdx.x;
#pragma unroll
    for (int it = 0; it < 4; ++it) {
        int lin = it * 256 + tid;
        int i = lin >> 4;
        int j4 = (lin & 15) * 4;
        float4 v = *(const float4*)(src + (size_t)(r0 + i) * C + c0 + j4);
        L[j4 + 0][i] = v.x; L[j4 + 1][i] = v.y; L[j4 + 2][i] = v.z; L[j4 + 3][i] = v.w;
    }
    __syncthreads();
#pragma unroll
    for (int it = 0; it < 4; ++it) {
        int lin = it * 256 + tid;
        int cc = lin >> 4;
        int r4 = (lin & 15) * 4;
        ushort4 o;
        o.x = f2bf(L[cc][r4 + 0]); o.y = f2bf(L[cc][r4 + 1]);
        o.z = f2bf(L[cc][r4 + 2]); o.w = f2bf(L[cc][r4 + 3]);
        *(ushort4*)(dst + (size_t)(c0 + cc) * R + r0 + r4) = o;
    }
}

// ---------------------------------------------------------------- fused Wq/Wk/Wv transpose
__global__ __launch_bounds__(256) void trans_qkv_kernel(const float* __restrict__ Wq,
                                                        const float* __restrict__ Wk,
                                                        const float* __restrict__ Wv,
                                                        unsigned short* __restrict__ dst) {
    __shared__ float L[64][68];
    const int z = blockIdx.z;
    const float* src = (z == 0) ? Wq : (z == 1) ? Wk : Wv;
    dst += (size_t)z * kE * kIn;
    const int c0 = blockIdx.x * 64, r0 = blockIdx.y * 64;   // c over E, r over In
    const int tid = threadIdx.x;
#pragma unroll
    for (int it = 0; it < 4; ++it) {
        int lin = it * 256 + tid;
        int i = lin >> 4;
        int j4 = (lin & 15) * 4;
        float4 v = *(const float4*)(src + (size_t)(r0 + i) * kE + c0 + j4);
        L[j4 + 0][i] = v.x; L[j4 + 1][i] = v.y; L[j4 + 2][i] = v.z; L[j4 + 3][i] = v.w;
    }
    __syncthreads();
#pragma unroll
    for (int it = 0; it < 4; ++it) {
        int lin = it * 256 + tid;
        int cc = lin >> 4;
        int r4 = (lin & 15) * 4;
        ushort4 o;
        o.x = f2bf(L[cc][r4 + 0]); o.y = f2bf(L[cc][r4 + 1]);
        o.z = f2bf(L[cc][r4 + 2]); o.w = f2bf(L[cc][r4 + 3]);
        *(ushort4*)(dst + (size_t)(c0 + cc) * kIn + r0 + r4) = o;
    }
}

// ================================================================ 128x256 BK=32 GEMM core
// 512 threads = 8 waves (2M x 4N); per-wave output 64x64 (acc[4][4] f32x4).
// LDS (48KB): As[2 x 8KB] + Bs[2 x 16KB], FRAGMENT layout:
//   A unit g=(wmg*4+i): slot lane l holds A[m0+wmg*64+i*16+(l&15)][k0+(l>>4)*8 ..8]
//   B unit u=(wng*4+j): slot lane l holds Bt[n0+wng*64+j*16+(l&15)][k0+(l>>4)*8 ..8]
// Staged via per-lane global source (inverse permutation); all ds_read_b128
// are lane-linear => conflict-free. 3 gload_lds/wave/K-tile; counted vmcnt(3).
__device__ __forceinline__ void gemm128_mainloop(const unsigned short* __restrict__ A,
                                                 const unsigned short* __restrict__ Bt,
                                                 int K, int m0, int n0,
                                                 unsigned short* As, unsigned short* Bs,
                                                 f32x4 (&acc)[4][4]) {
    const int tid = threadIdx.x, lane = tid & 63, w = tid >> 6;
    const int nt = K >> 5;

    // per-lane PERMUTED global sources (fragment-layout inverse):
    // stage-wave w, lane l fetches the element destined for LDS slot [unit][l].
    const int lrow = lane & 15, lchk = lane >> 4;
    const unsigned short* Agl =
        A + (size_t)(m0 + (w >> 2) * 64 + (w & 3) * 16 + lrow) * K + lchk * 8;
    const unsigned short* Bgl0 =
        Bt + (size_t)(n0 + (w >> 2) * 64 + (w & 3) * 16 + lrow) * K + lchk * 8;          // unit w
    const unsigned short* Bgl1 =
        Bt + (size_t)(n0 + ((w >> 2) + 2) * 64 + (w & 3) * 16 + lrow) * K + lchk * 8;    // unit w+8
    unsigned short* Asw = As + w * 512;            // 1KB per unit
    unsigned short* Bsw0 = Bs + w * 512;
    unsigned short* Bsw1 = Bs + (w + 8) * 512;

    auto stage = [&](int kt, int buf) {
        gload_lds16(Agl  + kt * 32, Asw  + buf * 4096);
        gload_lds16(Bgl0 + kt * 32, Bsw0 + buf * 8192);
        gload_lds16(Bgl1 + kt * 32, Bsw1 + buf * 8192);
    };

#pragma unroll
    for (int i = 0; i < 4; ++i)
#pragma unroll
        for (int j = 0; j < 4; ++j) acc[i][j] = (f32x4){0.f, 0.f, 0.f, 0.f};

    stage(0, 0);
    if (nt > 1) stage(1, 1);
    asm volatile("s_waitcnt vmcnt(3)" ::: "memory");   // tile0 landed; tile1 in flight
    __builtin_amdgcn_s_barrier();
    __builtin_amdgcn_sched_barrier(0);

    // consumer fragment bases (lane-linear, conflict-free)
    const unsigned short* Afb = As + ((w >> 2) * 4) * 512 + lane * 8;
    const unsigned short* Bfb = Bs + ((w & 3) * 4) * 512 + lane * 8;

    for (int t = 0; t < nt; ++t) {
        const int cur = t & 1;
        bf16x8 av[4], bv[4];
#pragma unroll
        for (int i = 0; i < 4; ++i)
            av[i] = *(const bf16x8*)(Afb + cur * 4096 + i * 512);
#pragma unroll
        for (int j = 0; j < 4; ++j)
            bv[j] = *(const bf16x8*)(Bfb + cur * 8192 + j * 512);
        asm volatile("s_waitcnt lgkmcnt(0)" ::: "memory");
        __builtin_amdgcn_sched_barrier(0);
        __builtin_amdgcn_s_barrier();          // all waves done reading buf[cur]
        if (t + 2 < nt) stage(t + 2, cur);     // refill freed buffer
        __builtin_amdgcn_sched_barrier(0);
#pragma unroll
        for (int i = 0; i < 4; ++i)
#pragma unroll
            for (int j = 0; j < 4; ++j)
                acc[i][j] = __builtin_amdgcn_mfma_f32_16x16x32_bf16(av[i], bv[j], acc[i][j], 0, 0, 0);
        if (t + 1 < nt) {
            __builtin_amdgcn_sched_barrier(0);
            if (t + 2 < nt) asm volatile("s_waitcnt vmcnt(3)" ::: "memory");
            else            asm volatile("s_waitcnt vmcnt(0)" ::: "memory");
            __builtin_amdgcn_sched_barrier(0);
            __builtin_amdgcn_s_barrier();      // tile t+1 visible
            __builtin_amdgcn_sched_barrier(0);
        }
    }
}

// ---------------------------------------------------------------- GEMM1: bf16 out
__global__ __launch_bounds__(512, 4) void gemm128_b16(const unsigned short* __restrict__ A,
                                                      const unsigned short* __restrict__ Bt,
                                                      unsigned short* __restrict__ C,
                                                      int N, int K, int ntN) {
    __shared__ unsigned short As[2 * 4096];
    __shared__ unsigned short Bs[2 * 8192];
    const int tid = threadIdx.x, lane = tid & 63, w = tid >> 6;
    const int col = lane & 15, quad = lane >> 4;
    const int wm = (w >> 2) * 64, wn = (w & 3) * 64;
    // XCD-chunked bijective swizzle (gridDim.x % 8 == 0)
    const int bid = blockIdx.x;
    const int qch = gridDim.x >> 3;
    const int swb = (bid & 7) * qch + (bid >> 3);
    const int mt = swb / ntN, ntl = swb - mt * ntN;
    const int m0 = mt * 128, n0 = ntl * 256;

    f32x4 acc[4][4];
    gemm128_mainloop(A, Bt, K, m0, n0, As, Bs, acc);

    // epilogue: per-wave LDS repack (reuses dead As region; per-wave private)
    float* Tw = (float*)As + w * 336;
    const int t2 = lane >> 2, n4 = (lane & 3) * 4;
#pragma unroll
    for (int ri = 0; ri < 4; ++ri)
#pragma unroll
        for (int cj = 0; cj < 4; ++cj) {
#pragma unroll
            for (int r = 0; r < 4; ++r)
                Tw[(quad * 4 + r) * 20 + col] = acc[ri][cj][r];
            float4 v = *(const float4*)&Tw[t2 * 20 + n4];
            ushort4 o;
            o.x = f2bf(v.x); o.y = f2bf(v.y); o.z = f2bf(v.z); o.w = f2bf(v.w);
            *(ushort4*)(C + (size_t)(m0 + wm + ri * 16 + t2) * N + n0 + wn + cj * 16 + n4) = o;
        }
}

// ---------------------------------------------------------------- GEMM2: attn @ Wo, fp32 transposed out
__global__ __launch_bounds__(512, 4) void gemm128_out(const unsigned short* __restrict__ A,
                                                      const unsigned short* __restrict__ Bt,
                                                      float* __restrict__ out,
                                                      int N, int K, int ntN) {
    __shared__ unsigned short As[2 * 4096];
    __shared__ unsigned short Bs[2 * 8192];
    const int tid = threadIdx.x, lane = tid & 63, w = tid >> 6;
    const int col = lane & 15, quad = lane >> 4;
    const int wm = (w >> 2) * 64, wn = (w & 3) * 64;
    const int bid = blockIdx.x;
    const int qch = gridDim.x >> 3;
    const int swb = (bid & 7) * qch + (bid >> 3);
    const int mt = swb / ntN, ntl = swb - mt * ntN;
    const int m0 = mt * 128, n0 = ntl * 256;

    f32x4 acc[4][4];
    gemm128_mainloop(A, Bt, K, m0, n0, As, Bs, acc);

    // epilogue: transpose per 16x16 fragment in per-wave LDS, store out[n][t] coalesced
    const int b = m0 >> 12, t0 = m0 & 4095;
    float* dst = out + (size_t)b * (kIn + kE) * kT + (size_t)kIn * kT;
    float* Tw = (float*)As + w * 336;
    const int n2 = lane >> 2, t4 = (lane & 3) * 4;
#pragma unroll
    for (int ri = 0; ri < 4; ++ri)
#pragma unroll
        for (int cj = 0; cj < 4; ++cj) {
            *(float4*)&Tw[col * 20 + quad * 4] =
                (float4){acc[ri][cj][0], acc[ri][cj][1], acc[ri][cj][2], acc[ri][cj][3]};
            float4 v = *(const float4*)&Tw[n2 * 20 + t4];
            *(float4*)(dst + (size_t)(n0 + wn + cj * 16 + n2) * kT + t0 + wm + ri * 16 + t4) = v;
        }
}

// ---------------------------------------------------------------- Phase A (MFMA): KV, Ksum
__global__ __launch_bounds__(256) void phaseA_mfma(const unsigned short* __restrict__ QKVb,
                                                   const unsigned short* __restrict__ projb,
                                                   float* __restrict__ KVg,
                                                   float* __restrict__ Ksumg) {
    __shared__ unsigned short Ks[64 * 64];     // [t][d] XOR-swizzled chunks
    __shared__ unsigned short VT[64 * 72];     // [d][t] pad 8
    __shared__ unsigned short KpT[256 * 72];   // [f][t] pad 8
    const int tid = threadIdx.x, lane = tid & 63, w = tid >> 6;
    const int col = lane & 15, quad = lane >> 4;
    const int bh = blockIdx.x, b = bh >> 4, h = bh & 15;
    const int grp = blockIdx.y;
    const int f0 = w * 64;
    const int swz = col & 7;

    bf16x8 bB[2][4];   // proj B-fragments, invariant
#pragma unroll
    for (int s = 0; s < 2; ++s)
#pragma unroll
        for (int j = 0; j < 4; ++j)
            bB[s][j] = *(const bf16x8*)(projb + (size_t)(f0 + j * 16 + col) * 64 + s * 32 + quad * 8);

    f32x4 kvacc[4][4];
#pragma unroll
    for (int i = 0; i < 4; ++i)
#pragma unroll
        for (int j = 0; j < 4; ++j) kvacc[i][j] = (f32x4){0.f, 0.f, 0.f, 0.f};
    float ksum_acc[4] = {0.f, 0.f, 0.f, 0.f};

    for (int it = 0; it < 8; ++it) {
        const size_t rowbase = (size_t)(b * kT + grp * 512 + it * 64) * kQKVs + h * kD;
        __syncthreads();
#pragma unroll
        for (int i2 = 0; i2 < 2; ++i2) {
            int p = (i2 * 4 + w) * 64 + lane;
            int row = p >> 3;
            int cg = ((p & 7) ^ (row & 7)) * 8;
            gload_lds16(QKVb + rowbase + 1024 + (size_t)row * kQKVs + cg, &Ks[(i2 * 4 + w) * 512]);
        }
#pragma unroll
        for (int r = 0; r < 4; ++r) {
            int lin = r * 256 + tid;
            int t = lin >> 4, d4 = (lin & 15) * 4;
            ushort4 v = *(const ushort4*)(QKVb + rowbase + 2048 + (size_t)t * kQKVs + d4);
            VT[(d4 + 0) * 72 + t] = v.x; VT[(d4 + 1) * 72 + t] = v.y;
            VT[(d4 + 2) * 72 + t] = v.z; VT[(d4 + 3) * 72 + t] = v.w;
        }
        __syncthreads();
        bf16x8 av[2][4];
#pragma unroll
        for (int s = 0; s < 2; ++s)
#pragma unroll
            for (int i = 0; i < 4; ++i)
                av[s][i] = *(const bf16x8*)&Ks[(i * 16 + col) * 64 + ((s * 4 + quad) ^ swz) * 8];
#pragma unroll
        for (int j = 0; j < 4; ++j) {
            f32x4 sa[4];
#pragma unroll
            for (int i = 0; i < 4; ++i) sa[i] = (f32x4){0.f, 0.f, 0.f, 0.f};
#pragma unroll
            for (int s = 0; s < 2; ++s)
#pragma unroll
                for (int i = 0; i < 4; ++i)
                    sa[i] = __builtin_amdgcn_mfma_f32_16x16x32_bf16(av[s][i], bB[s][j], sa[i], 0, 0, 0);
            const int f = f0 + j * 16 + col;
#pragma unroll
            for (int i = 0; i < 4; ++i) {
                float e0 = __expf(sa[i][0]) + 1e-6f;
                float e1 = __expf(sa[i][1]) + 1e-6f;
                float e2 = __expf(sa[i][2]) + 1e-6f;
                float e3 = __expf(sa[i][3]) + 1e-6f;
                ksum_acc[j] += (e0 + e1) + (e2 + e3);
                ushort4 pk;
                pk.x = f2bf(e0); pk.y = f2bf(e1); pk.z = f2bf(e2); pk.w = f2bf(e3);
                *(ushort4*)&KpT[f * 72 + i * 16 + quad * 4] = pk;
            }
        }
#pragma unroll
        for (int s = 0; s < 2; ++s) {
            const int kc = s * 32 + quad * 8;
            bf16x8 a2[4], b2[4];
#pragma unroll
            for (int i = 0; i < 4; ++i)
                a2[i] = *(const bf16x8*)&KpT[(f0 + i * 16 + col) * 72 + kc];
#pragma unroll
            for (int jn = 0; jn < 4; ++jn)
                b2[jn] = *(const bf16x8*)&VT[(jn * 16 + col) * 72 + kc];
#pragma unroll
            for (int i = 0; i < 4; ++i)
#pragma unroll
                for (int jn = 0; jn < 4; ++jn)
                    kvacc[i][jn] = __builtin_amdgcn_mfma_f32_16x16x32_bf16(a2[i], b2[jn], kvacc[i][jn], 0, 0, 0);
        }
    }
    const size_t kvbase = (size_t)bh * (kF * kD);
#pragma unroll
    for (int i = 0; i < 4; ++i)
#pragma unroll
        for (int jn = 0; jn < 4; ++jn)
#pragma unroll
            for (int r = 0; r < 4; ++r)
                atomicAdd(&KVg[kvbase + (size_t)(f0 + i * 16 + quad * 4 + r) * kD + jn * 16 + col],
                          kvacc[i][jn][r]);
#pragma unroll
    for (int j = 0; j < 4; ++j) {
        float v = ksum_acc[j];
        v += __shfl_xor(v, 16);
        v += __shfl_xor(v, 32);
        if (quad == 0) atomicAdd(&Ksumg[(size_t)bh * kF + f0 + j * 16 + col], v);
    }
}

// ---------------------------------------------------------------- Phase B (MFMA): attn bf16
__global__ __launch_bounds__(256) void phaseB_mfma(const unsigned short* __restrict__ QKVb,
                                                   const unsigned short* __restrict__ projb,
                                                   const unsigned short* __restrict__ KVTb,
                                                   const float* __restrict__ Ksumg,
                                                   unsigned short* __restrict__ attnb) {
    __shared__ unsigned short Qs[64 * 64];      // [t][d] XOR-swizzled chunks
    __shared__ unsigned short Qp[64 * 264];     // [t][f] pad 8
    __shared__ unsigned short KVTs[64 * 264];   // [d][f] pad 8
    __shared__ float KsS[256];
    __shared__ float denp[4][64];
    const int tid = threadIdx.x, lane = tid & 63, w = tid >> 6;
    const int col = lane & 15, quad = lane >> 4;
    const int bh = blockIdx.x, b = bh >> 4, h = bh & 15;
    const int grp = blockIdx.y;
    const int f0 = w * 64;
    const int swz = col & 7;

    bf16x8 bB[2][4];
#pragma unroll
    for (int s = 0; s < 2; ++s)
#pragma unroll
        for (int j = 0; j < 4; ++j)
            bB[s][j] = *(const bf16x8*)(projb + (size_t)(f0 + j * 16 + col) * 64 + s * 32 + quad * 8);

#pragma unroll
    for (int r = 0; r < 8; ++r) {
        int lin = r * 256 + tid;
        int d = lin >> 5, fc8 = (lin & 31) * 8;
        *(bf16x8*)&KVTs[d * 264 + fc8] = *(const bf16x8*)(KVTb + (size_t)bh * 16384 + d * 256 + fc8);
    }
    KsS[tid] = Ksumg[(size_t)bh * kF + tid];

    for (int it = 0; it < 8; ++it) {
        const int tg0 = grp * 512 + it * 64;
        const size_t rowbase = (size_t)(b * kT + tg0) * kQKVs + h * kD;
        __syncthreads();
#pragma unroll
        for (int i2 = 0; i2 < 2; ++i2) {
            int p = (i2 * 4 + w) * 64 + lane;
            int row = p >> 3;
            int cg = ((p & 7) ^ (row & 7)) * 8;
            gload_lds16(QKVb + rowbase + (size_t)row * kQKVs + cg, &Qs[(i2 * 4 + w) * 512]);
        }
        __syncthreads();
        bf16x8 av[2][4];
#pragma unroll
        for (int s = 0; s < 2; ++s)
#pragma unroll
            for (int i = 0; i < 4; ++i)
                av[s][i] = *(const bf16x8*)&Qs[(i * 16 + col) * 64 + ((s * 4 + quad) ^ swz) * 8];
#pragma unroll
        for (int j = 0; j < 4; ++j) {
            f32x4 sa[4];
#pragma unroll
            for (int i = 0; i < 4; ++i) sa[i] = (f32x4){0.f, 0.f, 0.f, 0.f};
#pragma unroll
            for (int s = 0; s < 2; ++s)
#pragma unroll
                for (int i = 0; i < 4; ++i)
                    sa[i] = __builtin_amdgcn_mfma_f32_16x16x32_bf16(av[s][i], bB[s][j], sa[i], 0, 0, 0);
            const int f = f0 + j * 16 + col;
#pragma unroll
            for (int i = 0; i < 4; ++i) {
                const int tb = i * 16 + quad * 4;
                Qp[(tb + 0) * 264 + f] = f2bf(__expf(sa[i][0]) + 1e-6f);
                Qp[(tb + 1) * 264 + f] = f2bf(__expf(sa[i][1]) + 1e-6f);
                Qp[(tb + 2) * 264 + f] = f2bf(__expf(sa[i][2]) + 1e-6f);
                Qp[(tb + 3) * 264 + f] = f2bf(__expf(sa[i][3]) + 1e-6f);
            }
        }
        float dp = 0.f;
#pragma unroll
        for (int u = 0; u < 64; u += 8) {
            bf16x8 qv = *(const bf16x8*)&Qp[lane * 264 + f0 + u];
#pragma unroll
            for (int k2 = 0; k2 < 8; ++k2)
                dp += bf2f((unsigned short)qv[k2]) * KsS[f0 + u + k2];
        }
        denp[w][lane] = dp;
        __syncthreads();
        f32x4 nacc[4];
#pragma unroll
        for (int jn = 0; jn < 4; ++jn) nacc[jn] = (f32x4){0.f, 0.f, 0.f, 0.f};
#pragma unroll
        for (int s = 0; s < 8; ++s) {
            const int kc = s * 32 + quad * 8;
            bf16x8 aq = *(const bf16x8*)&Qp[(w * 16 + col) * 264 + kc];
#pragma unroll
            for (int jn = 0; jn < 4; ++jn) {
                bf16x8 bk = *(const bf16x8*)&KVTs[(jn * 16 + col) * 264 + kc];
                nacc[jn] = __builtin_amdgcn_mfma_f32_16x16x32_bf16(aq, bk, nacc[jn], 0, 0, 0);
            }
        }
#pragma unroll
        for (int r = 0; r < 4; ++r) {
            const int tl = w * 16 + quad * 4 + r;
            float den = denp[0][tl] + denp[1][tl] + denp[2][tl] + denp[3][tl];
            float rd = 1.f / fmaxf(den, 1e-6f);
            const size_t ob = (size_t)(b * kT + tg0 + tl) * kE + h * kD;
#pragma unroll
            for (int jn = 0; jn < 4; ++jn)
                attnb[ob + jn * 16 + col] = f2bf(nacc[jn][r] * rd);
        }
    }
}

// ---------------------------------------------------------------- launch
extern "C" void kernel_launch(void* const* d_in, const int* in_sizes, int n_in,
                              void* d_out, int out_size, void* d_ws, size_t ws_size,
                              hipStream_t stream) {
    (void)in_sizes; (void)n_in; (void)out_size; (void)ws_size;
    const float* x    = (const float*)d_in[0];
    const float* Wq   = (const float*)d_in[1];
    const float* Wk   = (const float*)d_in[2];
    const float* Wv   = (const float*)d_in[3];
    const float* Wo   = (const float*)d_in[4];
    const float* proj = (const float*)d_in[5];
    float* out = (float*)d_out;

    char* ws = (char*)d_ws;
    unsigned short* QKVb  = (unsigned short*)(ws);               // 96MB
    unsigned short* attnb = (unsigned short*)(ws + 100663296);   // 32MB
    unsigned short* Abuf  = (unsigned short*)(ws + 100663296);   // aliases attnb (pre-gemm1)
    unsigned short* Btqkv = (unsigned short*)(ws + 134217728);   // 3MB
    unsigned short* WoT   = (unsigned short*)(ws + 137363456);   // 2MB
    unsigned short* projb = (unsigned short*)(ws + 139460608);   // 32KB
    float*          KVg   = (float*)(ws + 139493376);            // 4MB
    float*          Ksumg = (float*)(ws + 143687680);            // 64KB
    unsigned short* KVTb  = (unsigned short*)(ws + 143753216);   // 2MB

    copy_x_kernel<<<dim3(8192), 256, 0, stream>>>(x, out);

    trans_f2b_kernel<<<dim3(64, 8, 4), 256, 0, stream>>>(x, Abuf, kIn, kT,
                                                         (long)kIn * kT, (long)kT * kIn);
    trans_qkv_kernel<<<dim3(16, 8, 3), 256, 0, stream>>>(Wq, Wk, Wv, Btqkv);
    trans_f2b_kernel<<<dim3(16, 16, 1), 256, 0, stream>>>(Wo, WoT, kE, kE, 0, 0);
    f2b_flat_kernel<<<dim3(16), 256, 0, stream>>>(proj, projb, kF * kD / 4);

    // GEMM1: M=16384 x N=3072, K=512 -> 128 x 12 = 1536 tiles of 128x256
    gemm128_b16<<<dim3(1536), 512, 0, stream>>>(Abuf, Btqkv, QKVb, kQKVs, kIn, 12);

    const int nz = kB * kH * kF * kD + kB * kH * kF;
    zero_kernel<<<dim3((nz + 255) / 256), 256, 0, stream>>>(KVg, nz);

    phaseA_mfma<<<dim3(64, 8), 256, 0, stream>>>(QKVb, projb, KVg, Ksumg);
    trans_f2b_kernel<<<dim3(1, 4, 64), 256, 0, stream>>>(KVg, KVTb, kF, kD,
                                                         (long)kF * kD, (long)kF * kD);
    phaseB_mfma<<<dim3(64, 8), 256, 0, stream>>>(QKVb, projb, KVTb, Ksumg, attnb);

    // GEMM2: M=16384 x N=1024, K=1024 -> 128 x 4 = 512 tiles of 128x256
    gemm128_out<<<dim3(512), 512, 0, stream>>>(attnb, WoT, out, kE, kE, 4);
}

// Round 6
// 378.320 us; speedup vs baseline: 1.0274x; 1.0274x over previous
//
#include <hip/hip_runtime.h>

// PerformerAttnBlock — Round 10: in-cache-line XOR swizzle (coalesced staging
// + 2-way-free fragment reads), copy_x fused into x-transpose, phaseA grid 2x.
// GEMM: 128x256 tile BK=32, 8 waves, LDS 48KB (epilogue reuses As) -> 3 blk/CU.
// Swizzle: LDS[row][c] = global[row][c ^ ((row>>1)&3)] — permutes 16B chunks
// WITHIN each 64B row line (coalescer unaffected); fragment read uses
// chunk' = quad ^ ((col>>1)&3) -> all 8 bank-groups covered, 2-way residual.
// B=4, IN=512, T=4096, EMBED=1024, H=16, D=64, F=256.
// WS (bytes):
//   0         QKVb bf16 [16384][3072] (96MB)
//   100663296 attnb bf16 [16384][1024] (32MB)  -- Abuf bf16 [16384][512] aliases pre-gemm1
//   134217728 Btqkv bf16 [3072][512] (3MB)
//   137363456 WoT bf16 [1024][1024] (2MB)
//   139460608 projb bf16 [256][64] (32KB)
//   139493376 KVg fp32 [64][256][64] (4MB)
//   143687680 Ksumg fp32 [64][256] (64KB)
//   143753216 KVTb bf16 [64][64][256] (2MB)

constexpr int kB  = 4;
constexpr int kIn = 512;
constexpr int kT  = 4096;
constexpr int kE  = 1024;
constexpr int kH  = 16;
constexpr int kD  = 64;
constexpr int kF  = 256;
constexpr int kQKVs = 3072;

typedef __attribute__((ext_vector_type(8))) short bf16x8;
typedef __attribute__((ext_vector_type(4))) float f32x4;

__device__ __forceinline__ unsigned short f2bf(float f) {
    unsigned u = __float_as_uint(f);
    u += 0x7fff + ((u >> 16) & 1);          // RNE
    return (unsigned short)(u >> 16);
}
__device__ __forceinline__ float bf2f(unsigned short s) {
    return __uint_as_float(((unsigned)s) << 16);
}
__device__ __forceinline__ void gload_lds16(const void* g, void* l) {
    __builtin_amdgcn_global_load_lds((const __attribute__((address_space(1))) void*)g,
                                     (__attribute__((address_space(3))) void*)l, 16, 0, 0);
}

// ---------------------------------------------------------------- zero
__global__ __launch_bounds__(256) void zero_kernel(float* __restrict__ p, int n) {
    int i = blockIdx.x * 256 + threadIdx.x;
    if (i < n) p[i] = 0.f;
}

// ---------------------------------------------------------------- flat fp32->bf16
__global__ __launch_bounds__(256) void f2b_flat_kernel(const float* __restrict__ s,
                                                       unsigned short* __restrict__ d, int n4) {
    int i = blockIdx.x * 256 + threadIdx.x;
    if (i < n4) {
        float4 v = ((const float4*)s)[i];
        ushort4 o;
        o.x = f2bf(v.x); o.y = f2bf(v.y); o.z = f2bf(v.z); o.w = f2bf(v.w);
        ((ushort4*)d)[i] = o;
    }
}

// ---------------------------------------------------------------- fused: x -> out copy + x^T bf16
// reads x [b][512][4096] ONCE; writes out[:, :512, :] fp32 and Abuf [b*4096+t][512] bf16.
__global__ __launch_bounds__(256) void trans_xcopy_kernel(const float* __restrict__ x,
                                                          float* __restrict__ out,
                                                          unsigned short* __restrict__ dst) {
    __shared__ float L[64][68];
    const int b = blockIdx.z;
    const float* src = x + (size_t)b * kIn * kT;
    float4* outb = (float4*)out + (size_t)b * ((kIn + kE) * kT / 4);
    unsigned short* dstb = dst + (size_t)b * kT * kIn;
    const int c0 = blockIdx.x * 64, r0 = blockIdx.y * 64;   // c over T, r over In
    const int tid = threadIdx.x;
#pragma unroll
    for (int it = 0; it < 4; ++it) {
        int lin = it * 256 + tid;
        int i = lin >> 4;
        int j4 = (lin & 15) * 4;
        float4 v = *(const float4*)(src + (size_t)(r0 + i) * kT + c0 + j4);
        outb[((size_t)(r0 + i) * kT + c0 + j4) >> 2] = v;   // pass-through copy
        L[j4 + 0][i] = v.x; L[j4 + 1][i] = v.y; L[j4 + 2][i] = v.z; L[j4 + 3][i] = v.w;
    }
    __syncthreads();
#pragma unroll
    for (int it = 0; it < 4; ++it) {
        int lin = it * 256 + tid;
        int cc = lin >> 4;
        int r4 = (lin & 15) * 4;
        ushort4 o;
        o.x = f2bf(L[cc][r4 + 0]); o.y = f2bf(L[cc][r4 + 1]);
        o.z = f2bf(L[cc][r4 + 2]); o.w = f2bf(L[cc][r4 + 3]);
        *(ushort4*)(dstb + (size_t)(c0 + cc) * kIn + r0 + r4) = o;
    }
}

// ---------------------------------------------------------------- transpose + fp32->bf16
// src [R][C] fp32 (+z*sstride), dst [C][R] bf16 (+z*dstride)
__global__ __launch_bounds__(256) void trans_f2b_kernel(const float* __restrict__ src,
                                                        unsigned short* __restrict__ dst,
                                                        int R, int C,
                                                        long sstride, long dstride) {
    __shared__ float L[64][68];
    src += (size_t)blockIdx.z * sstride;
    dst += (size_t)blockIdx.z * dstride;
    const int c0 = blockIdx.x * 64, r0 = blockIdx.y * 64;
    const int tid = threadIdx.x;
#pragma unroll
    for (int it = 0; it < 4; ++it) {
        int lin = it * 256 + tid;
        int i = lin >> 4;
        int j4 = (lin & 15) * 4;
        float4 v = *(const float4*)(src + (size_t)(r0 + i) * C + c0 + j4);
        L[j4 + 0][i] = v.x; L[j4 + 1][i] = v.y; L[j4 + 2][i] = v.z; L[j4 + 3][i] = v.w;
    }
    __syncthreads();
#pragma unroll
    for (int it = 0; it < 4; ++it) {
        int lin = it * 256 + tid;
        int cc = lin >> 4;
        int r4 = (lin & 15) * 4;
        ushort4 o;
        o.x = f2bf(L[cc][r4 + 0]); o.y = f2bf(L[cc][r4 + 1]);
        o.z = f2bf(L[cc][r4 + 2]); o.w = f2bf(L[cc][r4 + 3]);
        *(ushort4*)(dst + (size_t)(c0 + cc) * R + r0 + r4) = o;
    }
}

// ---------------------------------------------------------------- fused Wq/Wk/Wv transpose
__global__ __launch_bounds__(256) void trans_qkv_kernel(const float* __restrict__ Wq,
                                                        const float* __restrict__ Wk,
                                                        const float* __restrict__ Wv,
                                                        unsigned short* __restrict__ dst) {
    __shared__ float L[64][68];
    const int z = blockIdx.z;
    const float* src = (z == 0) ? Wq : (z == 1) ? Wk : Wv;
    dst += (size_t)z * kE * kIn;
    const int c0 = blockIdx.x * 64, r0 = blockIdx.y * 64;   // c over E, r over In
    const int tid = threadIdx.x;
#pragma unroll
    for (int it = 0; it < 4; ++it) {
        int lin = it * 256 + tid;
        int i = lin >> 4;
        int j4 = (lin & 15) * 4;
        float4 v = *(const float4*)(src + (size_t)(r0 + i) * kE + c0 + j4);
        L[j4 + 0][i] = v.x; L[j4 + 1][i] = v.y; L[j4 + 2][i] = v.z; L[j4 + 3][i] = v.w;
    }
    __syncthreads();
#pragma unroll
    for (int it = 0; it < 4; ++it) {
        int lin = it * 256 + tid;
        int cc = lin >> 4;
        int r4 = (lin & 15) * 4;
        ushort4 o;
        o.x = f2bf(L[cc][r4 + 0]); o.y = f2bf(L[cc][r4 + 1]);
        o.z = f2bf(L[cc][r4 + 2]); o.w = f2bf(L[cc][r4 + 3]);
        *(ushort4*)(dst + (size_t)(c0 + cc) * kIn + r0 + r4) = o;
    }
}

// ================================================================ 128x256 BK=32 GEMM core
// 512 threads = 8 waves (2M x 4N); per-wave output 64x64 (acc[4][4] f32x4).
// LDS: dbuf x (A[128][32] + B[256][32]) bf16 = 48KB. In-line XOR swizzle:
// LDS[row][c16] = global[row][c16 ^ ((row>>1)&3)] (16B chunks within 64B row).
// Stage: 3 gload_lds/wave/K-tile, coalesced (permutation stays in-cache-line).
// Fragment read: chunk' = quad ^ ((col>>1)&3) -> 8 bank-groups, 2-way (free).
__device__ __forceinline__ void gemm128_mainloop(const unsigned short* __restrict__ A,
                                                 const unsigned short* __restrict__ Bt,
                                                 int K, int m0, int n0,
                                                 unsigned short* As, unsigned short* Bs,
                                                 f32x4 (&acc)[4][4]) {
    const int tid = threadIdx.x, lane = tid & 63, w = tid >> 6;
    const int col = lane & 15, quad = lane >> 4;
    const int wm = (w >> 2) * 64, wn = (w & 3) * 64;
    const int nt = K >> 5;

    // staging: row = tid>>2, source chunk = (tid&3) ^ ((row>>1)&3) — in-line perm
    const int srow = tid >> 2;
    const int schk = (tid & 3) ^ ((tid >> 3) & 3);
    const unsigned short* Agl  = A  + (size_t)(m0 + srow) * K + schk * 8;
    const unsigned short* Bgl0 = Bt + (size_t)(n0 + srow) * K + schk * 8;
    const unsigned short* Bgl1 = Bgl0 + (size_t)128 * K;     // rows+128: (row>>1)&3 unchanged
    unsigned short* Asw = As + w * 512;
    unsigned short* Bsw = Bs + w * 512;

    auto stage = [&](int kt, int buf) {
        gload_lds16(Agl  + kt * 32, Asw + buf * 4096);
        gload_lds16(Bgl0 + kt * 32, Bsw + buf * 8192);
        gload_lds16(Bgl1 + kt * 32, Bsw + buf * 8192 + 4096);
    };

#pragma unroll
    for (int i = 0; i < 4; ++i)
#pragma unroll
        for (int j = 0; j < 4; ++j) acc[i][j] = (f32x4){0.f, 0.f, 0.f, 0.f};

    stage(0, 0);
    if (nt > 1) stage(1, 1);
    asm volatile("s_waitcnt vmcnt(3)" ::: "memory");   // tile0 landed; tile1 in flight
    __builtin_amdgcn_s_barrier();
    __builtin_amdgcn_sched_barrier(0);

    const int rchk = (quad ^ ((col >> 1) & 3)) * 8;    // read-side chunk (elements)

    for (int t = 0; t < nt; ++t) {
        const int cur = t & 1;
        const unsigned short* Ab = As + cur * 4096;
        const unsigned short* Bb = Bs + cur * 8192;
        bf16x8 av[4], bv[4];
#pragma unroll
        for (int i = 0; i < 4; ++i)
            av[i] = *(const bf16x8*)&Ab[(wm + i * 16 + col) * 32 + rchk];
#pragma unroll
        for (int j = 0; j < 4; ++j)
            bv[j] = *(const bf16x8*)&Bb[(wn + j * 16 + col) * 32 + rchk];
        asm volatile("s_waitcnt lgkmcnt(0)" ::: "memory");
        __builtin_amdgcn_sched_barrier(0);
        __builtin_amdgcn_s_barrier();          // all waves done reading buf[cur]
        if (t + 2 < nt) stage(t + 2, cur);     // refill freed buffer
        __builtin_amdgcn_sched_barrier(0);
#pragma unroll
        for (int i = 0; i < 4; ++i)
#pragma unroll
            for (int j = 0; j < 4; ++j)
                acc[i][j] = __builtin_amdgcn_mfma_f32_16x16x32_bf16(av[i], bv[j], acc[i][j], 0, 0, 0);
        if (t + 1 < nt) {
            __builtin_amdgcn_sched_barrier(0);
            if (t + 2 < nt) asm volatile("s_waitcnt vmcnt(3)" ::: "memory");
            else            asm volatile("s_waitcnt vmcnt(0)" ::: "memory");
            __builtin_amdgcn_sched_barrier(0);
            __builtin_amdgcn_s_barrier();      // tile t+1 visible
            __builtin_amdgcn_sched_barrier(0);
        }
    }
}

// ---------------------------------------------------------------- GEMM1: bf16 out
__global__ __launch_bounds__(512, 4) void gemm128_b16(const unsigned short* __restrict__ A,
                                                      const unsigned short* __restrict__ Bt,
                                                      unsigned short* __restrict__ C,
                                                      int N, int K, int ntN) {
    __shared__ unsigned short As[2 * 4096];
    __shared__ unsigned short Bs[2 * 8192];
    const int tid = threadIdx.x, lane = tid & 63, w = tid >> 6;
    const int col = lane & 15, quad = lane >> 4;
    const int wm = (w >> 2) * 64, wn = (w & 3) * 64;
    // XCD-chunked bijective swizzle (gridDim.x % 8 == 0)
    const int bid = blockIdx.x;
    const int qch = gridDim.x >> 3;
    const int swb = (bid & 7) * qch + (bid >> 3);
    const int mt = swb / ntN, ntl = swb - mt * ntN;
    const int m0 = mt * 128, n0 = ntl * 256;

    f32x4 acc[4][4];
    gemm128_mainloop(A, Bt, K, m0, n0, As, Bs, acc);

    // epilogue: per-wave LDS repack in dead As (post-final-barrier, block-private)
    float* Tw = (float*)As + w * 336;
    const int t2 = lane >> 2, n4 = (lane & 3) * 4;
#pragma unroll
    for (int ri = 0; ri < 4; ++ri)
#pragma unroll
        for (int cj = 0; cj < 4; ++cj) {
#pragma unroll
            for (int r = 0; r < 4; ++r)
                Tw[(quad * 4 + r) * 20 + col] = acc[ri][cj][r];
            float4 v = *(const float4*)&Tw[t2 * 20 + n4];
            ushort4 o;
            o.x = f2bf(v.x); o.y = f2bf(v.y); o.z = f2bf(v.z); o.w = f2bf(v.w);
            *(ushort4*)(C + (size_t)(m0 + wm + ri * 16 + t2) * N + n0 + wn + cj * 16 + n4) = o;
        }
}

// ---------------------------------------------------------------- GEMM2: attn @ Wo, fp32 transposed out
__global__ __launch_bounds__(512, 4) void gemm128_out(const unsigned short* __restrict__ A,
                                                      const unsigned short* __restrict__ Bt,
                                                      float* __restrict__ out,
                                                      int N, int K, int ntN) {
    __shared__ unsigned short As[2 * 4096];
    __shared__ unsigned short Bs[2 * 8192];
    const int tid = threadIdx.x, lane = tid & 63, w = tid >> 6;
    const int col = lane & 15, quad = lane >> 4;
    const int wm = (w >> 2) * 64, wn = (w & 3) * 64;
    const int bid = blockIdx.x;
    const int qch = gridDim.x >> 3;
    const int swb = (bid & 7) * qch + (bid >> 3);
    const int mt = swb / ntN, ntl = swb - mt * ntN;
    const int m0 = mt * 128, n0 = ntl * 256;

    f32x4 acc[4][4];
    gemm128_mainloop(A, Bt, K, m0, n0, As, Bs, acc);

    // epilogue: transpose per 16x16 fragment in dead-As LDS, store out[n][t] coalesced
    const int b = m0 >> 12, t0 = m0 & 4095;
    float* dst = out + (size_t)b * (kIn + kE) * kT + (size_t)kIn * kT;
    float* Tw = (float*)As + w * 336;
    const int n2 = lane >> 2, t4 = (lane & 3) * 4;
#pragma unroll
    for (int ri = 0; ri < 4; ++ri)
#pragma unroll
        for (int cj = 0; cj < 4; ++cj) {
            *(float4*)&Tw[col * 20 + quad * 4] =
                (float4){acc[ri][cj][0], acc[ri][cj][1], acc[ri][cj][2], acc[ri][cj][3]};
            float4 v = *(const float4*)&Tw[n2 * 20 + t4];
            *(float4*)(dst + (size_t)(n0 + wn + cj * 16 + n2) * kT + t0 + wm + ri * 16 + t4) = v;
        }
}

// ---------------------------------------------------------------- Phase A (MFMA): KV, Ksum
// grid (64 bh, 16 grp): 1024 blocks (~3/CU, LDS 53KB-capped), 4 x 64-row tiles each.
__global__ __launch_bounds__(256) void phaseA_mfma(const unsigned short* __restrict__ QKVb,
                                                   const unsigned short* __restrict__ projb,
                                                   float* __restrict__ KVg,
                                                   float* __restrict__ Ksumg) {
    __shared__ unsigned short Ks[64 * 64];     // [t][d] XOR-swizzled chunks
    __shared__ unsigned short VT[64 * 72];     // [d][t] pad 8
    __shared__ unsigned short KpT[256 * 72];   // [f][t] pad 8
    const int tid = threadIdx.x, lane = tid & 63, w = tid >> 6;
    const int col = lane & 15, quad = lane >> 4;
    const int bh = blockIdx.x, b = bh >> 4, h = bh & 15;
    const int grp = blockIdx.y;
    const int f0 = w * 64;
    const int swz = col & 7;

    bf16x8 bB[2][4];   // proj B-fragments, invariant
#pragma unroll
    for (int s = 0; s < 2; ++s)
#pragma unroll
        for (int j = 0; j < 4; ++j)
            bB[s][j] = *(const bf16x8*)(projb + (size_t)(f0 + j * 16 + col) * 64 + s * 32 + quad * 8);

    f32x4 kvacc[4][4];
#pragma unroll
    for (int i = 0; i < 4; ++i)
#pragma unroll
        for (int j = 0; j < 4; ++j) kvacc[i][j] = (f32x4){0.f, 0.f, 0.f, 0.f};
    float ksum_acc[4] = {0.f, 0.f, 0.f, 0.f};

    for (int it = 0; it < 4; ++it) {
        const size_t rowbase = (size_t)(b * kT + grp * 256 + it * 64) * kQKVs + h * kD;
        __syncthreads();
#pragma unroll
        for (int i2 = 0; i2 < 2; ++i2) {
            int p = (i2 * 4 + w) * 64 + lane;
            int row = p >> 3;
            int cg = ((p & 7) ^ (row & 7)) * 8;
            gload_lds16(QKVb + rowbase + 1024 + (size_t)row * kQKVs + cg, &Ks[(i2 * 4 + w) * 512]);
        }
#pragma unroll
        for (int r = 0; r < 4; ++r) {
            int lin = r * 256 + tid;
            int t = lin >> 4, d4 = (lin & 15) * 4;
            ushort4 v = *(const ushort4*)(QKVb + rowbase + 2048 + (size_t)t * kQKVs + d4);
            VT[(d4 + 0) * 72 + t] = v.x; VT[(d4 + 1) * 72 + t] = v.y;
            VT[(d4 + 2) * 72 + t] = v.z; VT[(d4 + 3) * 72 + t] = v.w;
        }
        __syncthreads();
        bf16x8 av[2][4];
#pragma unroll
        for (int s = 0; s < 2; ++s)
#pragma unroll
            for (int i = 0; i < 4; ++i)
                av[s][i] = *(const bf16x8*)&Ks[(i * 16 + col) * 64 + ((s * 4 + quad) ^ swz) * 8];
#pragma unroll
        for (int j = 0; j < 4; ++j) {
            f32x4 sa[4];
#pragma unroll
            for (int i = 0; i < 4; ++i) sa[i] = (f32x4){0.f, 0.f, 0.f, 0.f};
#pragma unroll
            for (int s = 0; s < 2; ++s)
#pragma unroll
                for (int i = 0; i < 4; ++i)
                    sa[i] = __builtin_amdgcn_mfma_f32_16x16x32_bf16(av[s][i], bB[s][j], sa[i], 0, 0, 0);
            const int f = f0 + j * 16 + col;
#pragma unroll
            for (int i = 0; i < 4; ++i) {
                float e0 = __expf(sa[i][0]) + 1e-6f;
                float e1 = __expf(sa[i][1]) + 1e-6f;
                float e2 = __expf(sa[i][2]) + 1e-6f;
                float e3 = __expf(sa[i][3]) + 1e-6f;
                ksum_acc[j] += (e0 + e1) + (e2 + e3);
                ushort4 pk;
                pk.x = f2bf(e0); pk.y = f2bf(e1); pk.z = f2bf(e2); pk.w = f2bf(e3);
                *(ushort4*)&KpT[f * 72 + i * 16 + quad * 4] = pk;
            }
        }
#pragma unroll
        for (int s = 0; s < 2; ++s) {
            const int kc = s * 32 + quad * 8;
            bf16x8 a2[4], b2[4];
#pragma unroll
            for (int i = 0; i < 4; ++i)
                a2[i] = *(const bf16x8*)&KpT[(f0 + i * 16 + col) * 72 + kc];
#pragma unroll
            for (int jn = 0; jn < 4; ++jn)
                b2[jn] = *(const bf16x8*)&VT[(jn * 16 + col) * 72 + kc];
#pragma unroll
            for (int i = 0; i < 4; ++i)
#pragma unroll
                for (int jn = 0; jn < 4; ++jn)
                    kvacc[i][jn] = __builtin_amdgcn_mfma_f32_16x16x32_bf16(a2[i], b2[jn], kvacc[i][jn], 0, 0, 0);
        }
    }
    const size_t kvbase = (size_t)bh * (kF * kD);
#pragma unroll
    for (int i = 0; i < 4; ++i)
#pragma unroll
        for (int jn = 0; jn < 4; ++jn)
#pragma unroll
            for (int r = 0; r < 4; ++r)
                atomicAdd(&KVg[kvbase + (size_t)(f0 + i * 16 + quad * 4 + r) * kD + jn * 16 + col],
                          kvacc[i][jn][r]);
#pragma unroll
    for (int j = 0; j < 4; ++j) {
        float v = ksum_acc[j];
        v += __shfl_xor(v, 16);
        v += __shfl_xor(v, 32);
        if (quad == 0) atomicAdd(&Ksumg[(size_t)bh * kF + f0 + j * 16 + col], v);
    }
}

// ---------------------------------------------------------------- Phase B (MFMA): attn bf16
__global__ __launch_bounds__(256) void phaseB_mfma(const unsigned short* __restrict__ QKVb,
                                                   const unsigned short* __restrict__ projb,
                                                   const unsigned short* __restrict__ KVTb,
                                                   const float* __restrict__ Ksumg,
                                                   unsigned short* __restrict__ attnb) {
    __shared__ unsigned short Qs[64 * 64];      // [t][d] XOR-swizzled chunks
    __shared__ unsigned short Qp[64 * 264];     // [t][f] pad 8
    __shared__ unsigned short KVTs[64 * 264];   // [d][f] pad 8
    __shared__ float KsS[256];
    __shared__ float denp[4][64];
    const int tid = threadIdx.x, lane = tid & 63, w = tid >> 6;
    const int col = lane & 15, quad = lane >> 4;
    const int bh = blockIdx.x, b = bh >> 4, h = bh & 15;
    const int grp = blockIdx.y;
    const int f0 = w * 64;
    const int swz = col & 7;

    bf16x8 bB[2][4];
#pragma unroll
    for (int s = 0; s < 2; ++s)
#pragma unroll
        for (int j = 0; j < 4; ++j)
            bB[s][j] = *(const bf16x8*)(projb + (size_t)(f0 + j * 16 + col) * 64 + s * 32 + quad * 8);

#pragma unroll
    for (int r = 0; r < 8; ++r) {
        int lin = r * 256 + tid;
        int d = lin >> 5, fc8 = (lin & 31) * 8;
        *(bf16x8*)&KVTs[d * 264 + fc8] = *(const bf16x8*)(KVTb + (size_t)bh * 16384 + d * 256 + fc8);
    }
    KsS[tid] = Ksumg[(size_t)bh * kF + tid];

    for (int it = 0; it < 8; ++it) {
        const int tg0 = grp * 512 + it * 64;
        const size_t rowbase = (size_t)(b * kT + tg0) * kQKVs + h * kD;
        __syncthreads();
#pragma unroll
        for (int i2 = 0; i2 < 2; ++i2) {
            int p = (i2 * 4 + w) * 64 + lane;
            int row = p >> 3;
            int cg = ((p & 7) ^ (row & 7)) * 8;
            gload_lds16(QKVb + rowbase + (size_t)row * kQKVs + cg, &Qs[(i2 * 4 + w) * 512]);
        }
        __syncthreads();
        bf16x8 av[2][4];
#pragma unroll
        for (int s = 0; s < 2; ++s)
#pragma unroll
            for (int i = 0; i < 4; ++i)
                av[s][i] = *(const bf16x8*)&Qs[(i * 16 + col) * 64 + ((s * 4 + quad) ^ swz) * 8];
#pragma unroll
        for (int j = 0; j < 4; ++j) {
            f32x4 sa[4];
#pragma unroll
            for (int i = 0; i < 4; ++i) sa[i] = (f32x4){0.f, 0.f, 0.f, 0.f};
#pragma unroll
            for (int s = 0; s < 2; ++s)
#pragma unroll
                for (int i = 0; i < 4; ++i)
                    sa[i] = __builtin_amdgcn_mfma_f32_16x16x32_bf16(av[s][i], bB[s][j], sa[i], 0, 0, 0);
            const int f = f0 + j * 16 + col;
#pragma unroll
            for (int i = 0; i < 4; ++i) {
                const int tb = i * 16 + quad * 4;
                Qp[(tb + 0) * 264 + f] = f2bf(__expf(sa[i][0]) + 1e-6f);
                Qp[(tb + 1) * 264 + f] = f2bf(__expf(sa[i][1]) + 1e-6f);
                Qp[(tb + 2) * 264 + f] = f2bf(__expf(sa[i][2]) + 1e-6f);
                Qp[(tb + 3) * 264 + f] = f2bf(__expf(sa[i][3]) + 1e-6f);
            }
        }
        float dp = 0.f;
#pragma unroll
        for (int u = 0; u < 64; u += 8) {
            bf16x8 qv = *(const bf16x8*)&Qp[lane * 264 + f0 + u];
#pragma unroll
            for (int k2 = 0; k2 < 8; ++k2)
                dp += bf2f((unsigned short)qv[k2]) * KsS[f0 + u + k2];
        }
        denp[w][lane] = dp;
        __syncthreads();
        f32x4 nacc[4];
#pragma unroll
        for (int jn = 0; jn < 4; ++jn) nacc[jn] = (f32x4){0.f, 0.f, 0.f, 0.f};
#pragma unroll
        for (int s = 0; s < 8; ++s) {
            const int kc = s * 32 + quad * 8;
            bf16x8 aq = *(const bf16x8*)&Qp[(w * 16 + col) * 264 + kc];
#pragma unroll
            for (int jn = 0; jn < 4; ++jn) {
                bf16x8 bk = *(const bf16x8*)&KVTs[(jn * 16 + col) * 264 + kc];
                nacc[jn] = __builtin_amdgcn_mfma_f32_16x16x32_bf16(aq, bk, nacc[jn], 0, 0, 0);
            }
        }
#pragma unroll
        for (int r = 0; r < 4; ++r) {
            const int tl = w * 16 + quad * 4 + r;
            float den = denp[0][tl] + denp[1][tl] + denp[2][tl] + denp[3][tl];
            float rd = 1.f / fmaxf(den, 1e-6f);
            const size_t ob = (size_t)(b * kT + tg0 + tl) * kE + h * kD;
#pragma unroll
            for (int jn = 0; jn < 4; ++jn)
                attnb[ob + jn * 16 + col] = f2bf(nacc[jn][r] * rd);
        }
    }
}

// ---------------------------------------------------------------- launch
extern "C" void kernel_launch(void* const* d_in, const int* in_sizes, int n_in,
                              void* d_out, int out_size, void* d_ws, size_t ws_size,
                              hipStream_t stream) {
    (void)in_sizes; (void)n_in; (void)out_size; (void)ws_size;
    const float* x    = (const float*)d_in[0];
    const float* Wq   = (const float*)d_in[1];
    const float* Wk   = (const float*)d_in[2];
    const float* Wv   = (const float*)d_in[3];
    const float* Wo   = (const float*)d_in[4];
    const float* proj = (const float*)d_in[5];
    float* out = (float*)d_out;

    char* ws = (char*)d_ws;
    unsigned short* QKVb  = (unsigned short*)(ws);               // 96MB
    unsigned short* attnb = (unsigned short*)(ws + 100663296);   // 32MB
    unsigned short* Abuf  = (unsigned short*)(ws + 100663296);   // aliases attnb (pre-gemm1)
    unsigned short* Btqkv = (unsigned short*)(ws + 134217728);   // 3MB
    unsigned short* WoT   = (unsigned short*)(ws + 137363456);   // 2MB
    unsigned short* projb = (unsigned short*)(ws + 139460608);   // 32KB
    float*          KVg   = (float*)(ws + 139493376);            // 4MB
    float*          Ksumg = (float*)(ws + 143687680);            // 64KB
    unsigned short* KVTb  = (unsigned short*)(ws + 143753216);   // 2MB

    // fused: x -> out pass-through + x^T bf16 (x read once)
    trans_xcopy_kernel<<<dim3(64, 8, 4), 256, 0, stream>>>(x, out, Abuf);
    trans_qkv_kernel<<<dim3(16, 8, 3), 256, 0, stream>>>(Wq, Wk, Wv, Btqkv);
    trans_f2b_kernel<<<dim3(16, 16, 1), 256, 0, stream>>>(Wo, WoT, kE, kE, 0, 0);
    f2b_flat_kernel<<<dim3(16), 256, 0, stream>>>(proj, projb, kF * kD / 4);

    // GEMM1: M=16384 x N=3072, K=512 -> 128 x 12 = 1536 tiles of 128x256
    gemm128_b16<<<dim3(1536), 512, 0, stream>>>(Abuf, Btqkv, QKVb, kQKVs, kIn, 12);

    const int nz = kB * kH * kF * kD + kB * kH * kF;
    zero_kernel<<<dim3((nz + 255) / 256), 256, 0, stream>>>(KVg, nz);

    phaseA_mfma<<<dim3(64, 16), 256, 0, stream>>>(QKVb, projb, KVg, Ksumg);
    trans_f2b_kernel<<<dim3(1, 4, 64), 256, 0, stream>>>(KVg, KVTb, kF, kD,
                                                         (long)kF * kD, (long)kF * kD);
    phaseB_mfma<<<dim3(64, 8), 256, 0, stream>>>(QKVb, projb, KVTb, Ksumg, attnb);

    // GEMM2: M=16384 x N=1024, K=1024 -> 128 x 4 = 512 tiles of 128x256
    gemm128_out<<<dim3(512), 512, 0, stream>>>(attnb, WoT, out, kE, kE, 4);
}

// Round 7
// 360.196 us; speedup vs baseline: 1.0791x; 1.0503x over previous
//
#include <hip/hip_runtime.h>

// PerformerAttnBlock — Round 11: phaseA rebuilt (measured top kernel @82.5us,
// MfmaUtil 7.9%, 5.77M bank conflicts, 16.7M atomics).
// (a) grid reverted (64,8): halves atomic count to 8.4M;
// (b) VT transpose writes chunk-XOR swizzled: 8-way -> 2-way (free);
// (c) pipelined staging: Ks double-buffered + V reg ping-pong, raw s_barrier
//     with counted vmcnt(6) (K/V of tile t+1 stay in flight across barriers).
// GEMMs/transposes unchanged from Round 10 (gemm dropped below phaseA).
// B=4, IN=512, T=4096, EMBED=1024, H=16, D=64, F=256.
// WS (bytes):
//   0         QKVb bf16 [16384][3072] (96MB)
//   100663296 attnb bf16 [16384][1024] (32MB)  -- Abuf bf16 [16384][512] aliases pre-gemm1
//   134217728 Btqkv bf16 [3072][512] (3MB)
//   137363456 WoT bf16 [1024][1024] (2MB)
//   139460608 projb bf16 [256][64] (32KB)
//   139493376 KVg fp32 [64][256][64] (4MB)
//   143687680 Ksumg fp32 [64][256] (64KB)
//   143753216 KVTb bf16 [64][64][256] (2MB)

constexpr int kB  = 4;
constexpr int kIn = 512;
constexpr int kT  = 4096;
constexpr int kE  = 1024;
constexpr int kH  = 16;
constexpr int kD  = 64;
constexpr int kF  = 256;
constexpr int kQKVs = 3072;

typedef __attribute__((ext_vector_type(8))) short bf16x8;
typedef __attribute__((ext_vector_type(4))) float f32x4;

__device__ __forceinline__ unsigned short f2bf(float f) {
    unsigned u = __float_as_uint(f);
    u += 0x7fff + ((u >> 16) & 1);          // RNE
    return (unsigned short)(u >> 16);
}
__device__ __forceinline__ float bf2f(unsigned short s) {
    return __uint_as_float(((unsigned)s) << 16);
}
__device__ __forceinline__ void gload_lds16(const void* g, void* l) {
    __builtin_amdgcn_global_load_lds((const __attribute__((address_space(1))) void*)g,
                                     (__attribute__((address_space(3))) void*)l, 16, 0, 0);
}

// ---------------------------------------------------------------- zero
__global__ __launch_bounds__(256) void zero_kernel(float* __restrict__ p, int n) {
    int i = blockIdx.x * 256 + threadIdx.x;
    if (i < n) p[i] = 0.f;
}

// ---------------------------------------------------------------- flat fp32->bf16
__global__ __launch_bounds__(256) void f2b_flat_kernel(const float* __restrict__ s,
                                                       unsigned short* __restrict__ d, int n4) {
    int i = blockIdx.x * 256 + threadIdx.x;
    if (i < n4) {
        float4 v = ((const float4*)s)[i];
        ushort4 o;
        o.x = f2bf(v.x); o.y = f2bf(v.y); o.z = f2bf(v.z); o.w = f2bf(v.w);
        ((ushort4*)d)[i] = o;
    }
}

// ---------------------------------------------------------------- fused: x -> out copy + x^T bf16
__global__ __launch_bounds__(256) void trans_xcopy_kernel(const float* __restrict__ x,
                                                          float* __restrict__ out,
                                                          unsigned short* __restrict__ dst) {
    __shared__ float L[64][68];
    const int b = blockIdx.z;
    const float* src = x + (size_t)b * kIn * kT;
    float4* outb = (float4*)out + (size_t)b * ((kIn + kE) * kT / 4);
    unsigned short* dstb = dst + (size_t)b * kT * kIn;
    const int c0 = blockIdx.x * 64, r0 = blockIdx.y * 64;   // c over T, r over In
    const int tid = threadIdx.x;
#pragma unroll
    for (int it = 0; it < 4; ++it) {
        int lin = it * 256 + tid;
        int i = lin >> 4;
        int j4 = (lin & 15) * 4;
        float4 v = *(const float4*)(src + (size_t)(r0 + i) * kT + c0 + j4);
        outb[((size_t)(r0 + i) * kT + c0 + j4) >> 2] = v;   // pass-through copy
        L[j4 + 0][i] = v.x; L[j4 + 1][i] = v.y; L[j4 + 2][i] = v.z; L[j4 + 3][i] = v.w;
    }
    __syncthreads();
#pragma unroll
    for (int it = 0; it < 4; ++it) {
        int lin = it * 256 + tid;
        int cc = lin >> 4;
        int r4 = (lin & 15) * 4;
        ushort4 o;
        o.x = f2bf(L[cc][r4 + 0]); o.y = f2bf(L[cc][r4 + 1]);
        o.z = f2bf(L[cc][r4 + 2]); o.w = f2bf(L[cc][r4 + 3]);
        *(ushort4*)(dstb + (size_t)(c0 + cc) * kIn + r0 + r4) = o;
    }
}

// ---------------------------------------------------------------- transpose + fp32->bf16
__global__ __launch_bounds__(256) void trans_f2b_kernel(const float* __restrict__ src,
                                                        unsigned short* __restrict__ dst,
                                                        int R, int C,
                                                        long sstride, long dstride) {
    __shared__ float L[64][68];
    src += (size_t)blockIdx.z * sstride;
    dst += (size_t)blockIdx.z * dstride;
    const int c0 = blockIdx.x * 64, r0 = blockIdx.y * 64;
    const int tid = threadIdx.x;
#pragma unroll
    for (int it = 0; it < 4; ++it) {
        int lin = it * 256 + tid;
        int i = lin >> 4;
        int j4 = (lin & 15) * 4;
        float4 v = *(const float4*)(src + (size_t)(r0 + i) * C + c0 + j4);
        L[j4 + 0][i] = v.x; L[j4 + 1][i] = v.y; L[j4 + 2][i] = v.z; L[j4 + 3][i] = v.w;
    }
    __syncthreads();
#pragma unroll
    for (int it = 0; it < 4; ++it) {
        int lin = it * 256 + tid;
        int cc = lin >> 4;
        int r4 = (lin & 15) * 4;
        ushort4 o;
        o.x = f2bf(L[cc][r4 + 0]); o.y = f2bf(L[cc][r4 + 1]);
        o.z = f2bf(L[cc][r4 + 2]); o.w = f2bf(L[cc][r4 + 3]);
        *(ushort4*)(dst + (size_t)(c0 + cc) * R + r0 + r4) = o;
    }
}

// ---------------------------------------------------------------- fused Wq/Wk/Wv transpose
__global__ __launch_bounds__(256) void trans_qkv_kernel(const float* __restrict__ Wq,
                                                        const float* __restrict__ Wk,
                                                        const float* __restrict__ Wv,
                                                        unsigned short* __restrict__ dst) {
    __shared__ float L[64][68];
    const int z = blockIdx.z;
    const float* src = (z == 0) ? Wq : (z == 1) ? Wk : Wv;
    dst += (size_t)z * kE * kIn;
    const int c0 = blockIdx.x * 64, r0 = blockIdx.y * 64;   // c over E, r over In
    const int tid = threadIdx.x;
#pragma unroll
    for (int it = 0; it < 4; ++it) {
        int lin = it * 256 + tid;
        int i = lin >> 4;
        int j4 = (lin & 15) * 4;
        float4 v = *(const float4*)(src + (size_t)(r0 + i) * kE + c0 + j4);
        L[j4 + 0][i] = v.x; L[j4 + 1][i] = v.y; L[j4 + 2][i] = v.z; L[j4 + 3][i] = v.w;
    }
    __syncthreads();
#pragma unroll
    for (int it = 0; it < 4; ++it) {
        int lin = it * 256 + tid;
        int cc = lin >> 4;
        int r4 = (lin & 15) * 4;
        ushort4 o;
        o.x = f2bf(L[cc][r4 + 0]); o.y = f2bf(L[cc][r4 + 1]);
        o.z = f2bf(L[cc][r4 + 2]); o.w = f2bf(L[cc][r4 + 3]);
        *(ushort4*)(dst + (size_t)(c0 + cc) * kIn + r0 + r4) = o;
    }
}

// ================================================================ 128x256 BK=32 GEMM core
__device__ __forceinline__ void gemm128_mainloop(const unsigned short* __restrict__ A,
                                                 const unsigned short* __restrict__ Bt,
                                                 int K, int m0, int n0,
                                                 unsigned short* As, unsigned short* Bs,
                                                 f32x4 (&acc)[4][4]) {
    const int tid = threadIdx.x, lane = tid & 63, w = tid >> 6;
    const int col = lane & 15, quad = lane >> 4;
    const int wm = (w >> 2) * 64, wn = (w & 3) * 64;
    const int nt = K >> 5;

    const int srow = tid >> 2;
    const int schk = (tid & 3) ^ ((tid >> 3) & 3);
    const unsigned short* Agl  = A  + (size_t)(m0 + srow) * K + schk * 8;
    const unsigned short* Bgl0 = Bt + (size_t)(n0 + srow) * K + schk * 8;
    const unsigned short* Bgl1 = Bgl0 + (size_t)128 * K;
    unsigned short* Asw = As + w * 512;
    unsigned short* Bsw = Bs + w * 512;

    auto stage = [&](int kt, int buf) {
        gload_lds16(Agl  + kt * 32, Asw + buf * 4096);
        gload_lds16(Bgl0 + kt * 32, Bsw + buf * 8192);
        gload_lds16(Bgl1 + kt * 32, Bsw + buf * 8192 + 4096);
    };

#pragma unroll
    for (int i = 0; i < 4; ++i)
#pragma unroll
        for (int j = 0; j < 4; ++j) acc[i][j] = (f32x4){0.f, 0.f, 0.f, 0.f};

    stage(0, 0);
    if (nt > 1) stage(1, 1);
    asm volatile("s_waitcnt vmcnt(3)" ::: "memory");
    __builtin_amdgcn_s_barrier();
    __builtin_amdgcn_sched_barrier(0);

    const int rchk = (quad ^ ((col >> 1) & 3)) * 8;

    for (int t = 0; t < nt; ++t) {
        const int cur = t & 1;
        const unsigned short* Ab = As + cur * 4096;
        const unsigned short* Bb = Bs + cur * 8192;
        bf16x8 av[4], bv[4];
#pragma unroll
        for (int i = 0; i < 4; ++i)
            av[i] = *(const bf16x8*)&Ab[(wm + i * 16 + col) * 32 + rchk];
#pragma unroll
        for (int j = 0; j < 4; ++j)
            bv[j] = *(const bf16x8*)&Bb[(wn + j * 16 + col) * 32 + rchk];
        asm volatile("s_waitcnt lgkmcnt(0)" ::: "memory");
        __builtin_amdgcn_sched_barrier(0);
        __builtin_amdgcn_s_barrier();
        if (t + 2 < nt) stage(t + 2, cur);
        __builtin_amdgcn_sched_barrier(0);
#pragma unroll
        for (int i = 0; i < 4; ++i)
#pragma unroll
            for (int j = 0; j < 4; ++j)
                acc[i][j] = __builtin_amdgcn_mfma_f32_16x16x32_bf16(av[i], bv[j], acc[i][j], 0, 0, 0);
        if (t + 1 < nt) {
            __builtin_amdgcn_sched_barrier(0);
            if (t + 2 < nt) asm volatile("s_waitcnt vmcnt(3)" ::: "memory");
            else            asm volatile("s_waitcnt vmcnt(0)" ::: "memory");
            __builtin_amdgcn_sched_barrier(0);
            __builtin_amdgcn_s_barrier();
            __builtin_amdgcn_sched_barrier(0);
        }
    }
}

// ---------------------------------------------------------------- GEMM1: bf16 out
__global__ __launch_bounds__(512, 4) void gemm128_b16(const unsigned short* __restrict__ A,
                                                      const unsigned short* __restrict__ Bt,
                                                      unsigned short* __restrict__ C,
                                                      int N, int K, int ntN) {
    __shared__ unsigned short As[2 * 4096];
    __shared__ unsigned short Bs[2 * 8192];
    const int tid = threadIdx.x, lane = tid & 63, w = tid >> 6;
    const int col = lane & 15, quad = lane >> 4;
    const int wm = (w >> 2) * 64, wn = (w & 3) * 64;
    const int bid = blockIdx.x;
    const int qch = gridDim.x >> 3;
    const int swb = (bid & 7) * qch + (bid >> 3);
    const int mt = swb / ntN, ntl = swb - mt * ntN;
    const int m0 = mt * 128, n0 = ntl * 256;

    f32x4 acc[4][4];
    gemm128_mainloop(A, Bt, K, m0, n0, As, Bs, acc);

    float* Tw = (float*)As + w * 336;
    const int t2 = lane >> 2, n4 = (lane & 3) * 4;
#pragma unroll
    for (int ri = 0; ri < 4; ++ri)
#pragma unroll
        for (int cj = 0; cj < 4; ++cj) {
#pragma unroll
            for (int r = 0; r < 4; ++r)
                Tw[(quad * 4 + r) * 20 + col] = acc[ri][cj][r];
            float4 v = *(const float4*)&Tw[t2 * 20 + n4];
            ushort4 o;
            o.x = f2bf(v.x); o.y = f2bf(v.y); o.z = f2bf(v.z); o.w = f2bf(v.w);
            *(ushort4*)(C + (size_t)(m0 + wm + ri * 16 + t2) * N + n0 + wn + cj * 16 + n4) = o;
        }
}

// ---------------------------------------------------------------- GEMM2: attn @ Wo, fp32 transposed out
__global__ __launch_bounds__(512, 4) void gemm128_out(const unsigned short* __restrict__ A,
                                                      const unsigned short* __restrict__ Bt,
                                                      float* __restrict__ out,
                                                      int N, int K, int ntN) {
    __shared__ unsigned short As[2 * 4096];
    __shared__ unsigned short Bs[2 * 8192];
    const int tid = threadIdx.x, lane = tid & 63, w = tid >> 6;
    const int col = lane & 15, quad = lane >> 4;
    const int wm = (w >> 2) * 64, wn = (w & 3) * 64;
    const int bid = blockIdx.x;
    const int qch = gridDim.x >> 3;
    const int swb = (bid & 7) * qch + (bid >> 3);
    const int mt = swb / ntN, ntl = swb - mt * ntN;
    const int m0 = mt * 128, n0 = ntl * 256;

    f32x4 acc[4][4];
    gemm128_mainloop(A, Bt, K, m0, n0, As, Bs, acc);

    const int b = m0 >> 12, t0 = m0 & 4095;
    float* dst = out + (size_t)b * (kIn + kE) * kT + (size_t)kIn * kT;
    float* Tw = (float*)As + w * 336;
    const int n2 = lane >> 2, t4 = (lane & 3) * 4;
#pragma unroll
    for (int ri = 0; ri < 4; ++ri)
#pragma unroll
        for (int cj = 0; cj < 4; ++cj) {
            *(float4*)&Tw[col * 20 + quad * 4] =
                (float4){acc[ri][cj][0], acc[ri][cj][1], acc[ri][cj][2], acc[ri][cj][3]};
            float4 v = *(const float4*)&Tw[n2 * 20 + t4];
            *(float4*)(dst + (size_t)(n0 + wn + cj * 16 + n2) * kT + t0 + wm + ri * 16 + t4) = v;
        }
}

// ---------------------------------------------------------------- Phase A (MFMA): KV, Ksum
// grid (64 bh, 8 grp). Pipelined: Ks dbuf + V reg ping-pong, counted vmcnt(6),
// raw barriers (no vmcnt drain). VT chunk-XOR swizzled (write 2-way, read 2-way).
__global__ __launch_bounds__(256) void phaseA_mfma(const unsigned short* __restrict__ QKVb,
                                                   const unsigned short* __restrict__ projb,
                                                   float* __restrict__ KVg,
                                                   float* __restrict__ Ksumg) {
    __shared__ unsigned short Ks[2 * 4096];    // dbuf [t][d], XOR chunk staging
    __shared__ unsigned short VT[64 * 72];     // [d][t], chunk-XOR swizzled
    __shared__ unsigned short KpT[256 * 72];   // [f][t] (per-wave rows)
    const int tid = threadIdx.x, lane = tid & 63, w = tid >> 6;
    const int col = lane & 15, quad = lane >> 4;
    const int bh = blockIdx.x, b = bh >> 4, h = bh & 15;
    const int grp = blockIdx.y;
    const int f0 = w * 64;
    const int swz = col & 7;

    // K staging (pre-swizzled global source, linear LDS dest) — 2 units/thread
    const int p0 = w * 64 + lane, p1 = (4 + w) * 64 + lane;
    const int krow0 = p0 >> 3, kcg0 = ((p0 & 7) ^ (krow0 & 7)) * 8;
    const int krow1 = p1 >> 3, kcg1 = ((p1 & 7) ^ (krow1 & 7)) * 8;
    // V geometry: per r: row t = r*16 + (tid>>4), cols d4..d4+3
    const int vt_t = tid >> 4, vd4 = (tid & 15) * 4;
    const int vsw = (vd4 >> 2) & 7;

    const size_t base0 = (size_t)(b * kT + grp * 512) * kQKVs + h * kD;

    bf16x8 bB[2][4];
#pragma unroll
    for (int s = 0; s < 2; ++s)
#pragma unroll
        for (int j = 0; j < 4; ++j)
            bB[s][j] = *(const bf16x8*)(projb + (size_t)(f0 + j * 16 + col) * 64 + s * 32 + quad * 8);

    f32x4 kvacc[4][4];
#pragma unroll
    for (int i = 0; i < 4; ++i)
#pragma unroll
        for (int j = 0; j < 4; ++j) kvacc[i][j] = (f32x4){0.f, 0.f, 0.f, 0.f};
    float ksum_acc[4] = {0.f, 0.f, 0.f, 0.f};

    ushort4 vrA[4], vrB[4];

    auto kissue = [&](int it, int buf) {
        const size_t rb = base0 + (size_t)(it * 64) * kQKVs + 1024;
        gload_lds16(QKVb + rb + (size_t)krow0 * kQKVs + kcg0, &Ks[buf * 4096 + w * 512]);
        gload_lds16(QKVb + rb + (size_t)krow1 * kQKVs + kcg1, &Ks[buf * 4096 + (4 + w) * 512]);
    };
    auto vload = [&](int it, ushort4* vr) {
        const size_t rb = base0 + (size_t)(it * 64) * kQKVs + 2048;
#pragma unroll
        for (int r = 0; r < 4; ++r)
            vr[r] = *(const ushort4*)(QKVb + rb + (size_t)(r * 16 + vt_t) * kQKVs + vd4);
    };
    auto vtwrite = [&](const ushort4* vr) {
#pragma unroll
        for (int r = 0; r < 4; ++r) {
            const int t = r * 16 + vt_t;
            const int bo = (((t >> 3) ^ vsw) * 8) + (t & 7);
            VT[(vd4 + 0) * 72 + bo] = vr[r].x;
            VT[(vd4 + 1) * 72 + bo] = vr[r].y;
            VT[(vd4 + 2) * 72 + bo] = vr[r].z;
            VT[(vd4 + 3) * 72 + bo] = vr[r].w;
        }
    };

    // prologue: tiles 0,1 in flight; VT(0) built
    kissue(0, 0); vload(0, vrA);
    kissue(1, 1); vload(1, vrB);
    asm volatile("s_waitcnt vmcnt(6)" ::: "memory");   // K0+V0 landed
    __builtin_amdgcn_sched_barrier(0);
    vtwrite(vrA);
    asm volatile("s_waitcnt lgkmcnt(0)" ::: "memory");
    __builtin_amdgcn_sched_barrier(0);
    __builtin_amdgcn_s_barrier();
    __builtin_amdgcn_sched_barrier(0);

#pragma unroll 2
    for (int it = 0; it < 8; ++it) {
        const int cur = it & 1;
        // ---- proj MFMA: sa = K(it) @ proj^T
        bf16x8 av[2][4];
#pragma unroll
        for (int s = 0; s < 2; ++s)
#pragma unroll
            for (int i = 0; i < 4; ++i)
                av[s][i] = *(const bf16x8*)&Ks[cur * 4096 + (i * 16 + col) * 64 + ((s * 4 + quad) ^ swz) * 8];
#pragma unroll
        for (int j = 0; j < 4; ++j) {
            f32x4 sa[4];
#pragma unroll
            for (int i = 0; i < 4; ++i) sa[i] = (f32x4){0.f, 0.f, 0.f, 0.f};
#pragma unroll
            for (int s = 0; s < 2; ++s)
#pragma unroll
                for (int i = 0; i < 4; ++i)
                    sa[i] = __builtin_amdgcn_mfma_f32_16x16x32_bf16(av[s][i], bB[s][j], sa[i], 0, 0, 0);
            const int f = f0 + j * 16 + col;
#pragma unroll
            for (int i = 0; i < 4; ++i) {
                float e0 = __expf(sa[i][0]) + 1e-6f;
                float e1 = __expf(sa[i][1]) + 1e-6f;
                float e2 = __expf(sa[i][2]) + 1e-6f;
                float e3 = __expf(sa[i][3]) + 1e-6f;
                ksum_acc[j] += (e0 + e1) + (e2 + e3);
                ushort4 pk;
                pk.x = f2bf(e0); pk.y = f2bf(e1); pk.z = f2bf(e2); pk.w = f2bf(e3);
                *(ushort4*)&KpT[f * 72 + i * 16 + quad * 4] = pk;
            }
        }
        // ---- KV MFMA: kvacc += Kp^T(it) @ V(it)   (KpT per-wave; VT swizzled read)
#pragma unroll
        for (int s = 0; s < 2; ++s) {
            const int kc = s * 32 + quad * 8;
            bf16x8 a2[4], b2[4];
#pragma unroll
            for (int i = 0; i < 4; ++i)
                a2[i] = *(const bf16x8*)&KpT[(f0 + i * 16 + col) * 72 + kc];
#pragma unroll
            for (int jn = 0; jn < 4; ++jn) {
                const int d = jn * 16 + col;
                b2[jn] = *(const bf16x8*)&VT[d * 72 + (((s * 4 + quad) ^ ((d >> 2) & 7)) * 8)];
            }
#pragma unroll
            for (int i = 0; i < 4; ++i)
#pragma unroll
                for (int jn = 0; jn < 4; ++jn)
                    kvacc[i][jn] = __builtin_amdgcn_mfma_f32_16x16x32_bf16(a2[i], b2[jn], kvacc[i][jn], 0, 0, 0);
        }
        // ---- pipeline advance
        if (it < 7) {
            __builtin_amdgcn_sched_barrier(0);
            __builtin_amdgcn_s_barrier();              // VT(it)/Ks[cur] consumed
            __builtin_amdgcn_sched_barrier(0);
            if (it < 6) {
                kissue(it + 2, cur);
                vload(it + 2, (it & 1) ? vrB : vrA);
                asm volatile("s_waitcnt vmcnt(6)" ::: "memory");   // tile it+1 landed
            } else {
                asm volatile("s_waitcnt vmcnt(0)" ::: "memory");   // drain last
            }
            __builtin_amdgcn_sched_barrier(0);
            vtwrite((it & 1) ? vrA : vrB);             // VT(it+1)
            asm volatile("s_waitcnt lgkmcnt(0)" ::: "memory");
            __builtin_amdgcn_sched_barrier(0);
            __builtin_amdgcn_s_barrier();
            __builtin_amdgcn_sched_barrier(0);
        }
    }

    const size_t kvbase = (size_t)bh * (kF * kD);
#pragma unroll
    for (int i = 0; i < 4; ++i)
#pragma unroll
        for (int jn = 0; jn < 4; ++jn)
#pragma unroll
            for (int r = 0; r < 4; ++r)
                atomicAdd(&KVg[kvbase + (size_t)(f0 + i * 16 + quad * 4 + r) * kD + jn * 16 + col],
                          kvacc[i][jn][r]);
#pragma unroll
    for (int j = 0; j < 4; ++j) {
        float v = ksum_acc[j];
        v += __shfl_xor(v, 16);
        v += __shfl_xor(v, 32);
        if (quad == 0) atomicAdd(&Ksumg[(size_t)bh * kF + f0 + j * 16 + col], v);
    }
}

// ---------------------------------------------------------------- Phase B (MFMA): attn bf16
__global__ __launch_bounds__(256) void phaseB_mfma(const unsigned short* __restrict__ QKVb,
                                                   const unsigned short* __restrict__ projb,
                                                   const unsigned short* __restrict__ KVTb,
                                                   const float* __restrict__ Ksumg,
                                                   unsigned short* __restrict__ attnb) {
    __shared__ unsigned short Qs[64 * 64];      // [t][d] XOR-swizzled chunks
    __shared__ unsigned short Qp[64 * 264];     // [t][f] pad 8
    __shared__ unsigned short KVTs[64 * 264];   // [d][f] pad 8
    __shared__ float KsS[256];
    __shared__ float denp[4][64];
    const int tid = threadIdx.x, lane = tid & 63, w = tid >> 6;
    const int col = lane & 15, quad = lane >> 4;
    const int bh = blockIdx.x, b = bh >> 4, h = bh & 15;
    const int grp = blockIdx.y;
    const int f0 = w * 64;
    const int swz = col & 7;

    bf16x8 bB[2][4];
#pragma unroll
    for (int s = 0; s < 2; ++s)
#pragma unroll
        for (int j = 0; j < 4; ++j)
            bB[s][j] = *(const bf16x8*)(projb + (size_t)(f0 + j * 16 + col) * 64 + s * 32 + quad * 8);

#pragma unroll
    for (int r = 0; r < 8; ++r) {
        int lin = r * 256 + tid;
        int d = lin >> 5, fc8 = (lin & 31) * 8;
        *(bf16x8*)&KVTs[d * 264 + fc8] = *(const bf16x8*)(KVTb + (size_t)bh * 16384 + d * 256 + fc8);
    }
    KsS[tid] = Ksumg[(size_t)bh * kF + tid];

    for (int it = 0; it < 8; ++it) {
        const int tg0 = grp * 512 + it * 64;
        const size_t rowbase = (size_t)(b * kT + tg0) * kQKVs + h * kD;
        __syncthreads();
#pragma unroll
        for (int i2 = 0; i2 < 2; ++i2) {
            int p = (i2 * 4 + w) * 64 + lane;
            int row = p >> 3;
            int cg = ((p & 7) ^ (row & 7)) * 8;
            gload_lds16(QKVb + rowbase + (size_t)row * kQKVs + cg, &Qs[(i2 * 4 + w) * 512]);
        }
        __syncthreads();
        bf16x8 av[2][4];
#pragma unroll
        for (int s = 0; s < 2; ++s)
#pragma unroll
            for (int i = 0; i < 4; ++i)
                av[s][i] = *(const bf16x8*)&Qs[(i * 16 + col) * 64 + ((s * 4 + quad) ^ swz) * 8];
#pragma unroll
        for (int j = 0; j < 4; ++j) {
            f32x4 sa[4];
#pragma unroll
            for (int i = 0; i < 4; ++i) sa[i] = (f32x4){0.f, 0.f, 0.f, 0.f};
#pragma unroll
            for (int s = 0; s < 2; ++s)
#pragma unroll
                for (int i = 0; i < 4; ++i)
                    sa[i] = __builtin_amdgcn_mfma_f32_16x16x32_bf16(av[s][i], bB[s][j], sa[i], 0, 0, 0);
            const int f = f0 + j * 16 + col;
#pragma unroll
            for (int i = 0; i < 4; ++i) {
                const int tb = i * 16 + quad * 4;
                Qp[(tb + 0) * 264 + f] = f2bf(__expf(sa[i][0]) + 1e-6f);
                Qp[(tb + 1) * 264 + f] = f2bf(__expf(sa[i][1]) + 1e-6f);
                Qp[(tb + 2) * 264 + f] = f2bf(__expf(sa[i][2]) + 1e-6f);
                Qp[(tb + 3) * 264 + f] = f2bf(__expf(sa[i][3]) + 1e-6f);
            }
        }
        float dp = 0.f;
#pragma unroll
        for (int u = 0; u < 64; u += 8) {
            bf16x8 qv = *(const bf16x8*)&Qp[lane * 264 + f0 + u];
#pragma unroll
            for (int k2 = 0; k2 < 8; ++k2)
                dp += bf2f((unsigned short)qv[k2]) * KsS[f0 + u + k2];
        }
        denp[w][lane] = dp;
        __syncthreads();
        f32x4 nacc[4];
#pragma unroll
        for (int jn = 0; jn < 4; ++jn) nacc[jn] = (f32x4){0.f, 0.f, 0.f, 0.f};
#pragma unroll
        for (int s = 0; s < 8; ++s) {
            const int kc = s * 32 + quad * 8;
            bf16x8 aq = *(const bf16x8*)&Qp[(w * 16 + col) * 264 + kc];
#pragma unroll
            for (int jn = 0; jn < 4; ++jn) {
                bf16x8 bk = *(const bf16x8*)&KVTs[(jn * 16 + col) * 264 + kc];
                nacc[jn] = __builtin_amdgcn_mfma_f32_16x16x32_bf16(aq, bk, nacc[jn], 0, 0, 0);
            }
        }
#pragma unroll
        for (int r = 0; r < 4; ++r) {
            const int tl = w * 16 + quad * 4 + r;
            float den = denp[0][tl] + denp[1][tl] + denp[2][tl] + denp[3][tl];
            float rd = 1.f / fmaxf(den, 1e-6f);
            const size_t ob = (size_t)(b * kT + tg0 + tl) * kE + h * kD;
#pragma unroll
            for (int jn = 0; jn < 4; ++jn)
                attnb[ob + jn * 16 + col] = f2bf(nacc[jn][r] * rd);
        }
    }
}

// ---------------------------------------------------------------- launch
extern "C" void kernel_launch(void* const* d_in, const int* in_sizes, int n_in,
                              void* d_out, int out_size, void* d_ws, size_t ws_size,
                              hipStream_t stream) {
    (void)in_sizes; (void)n_in; (void)out_size; (void)ws_size;
    const float* x    = (const float*)d_in[0];
    const float* Wq   = (const float*)d_in[1];
    const float* Wk   = (const float*)d_in[2];
    const float* Wv   = (const float*)d_in[3];
    const float* Wo   = (const float*)d_in[4];
    const float* proj = (const float*)d_in[5];
    float* out = (float*)d_out;

    char* ws = (char*)d_ws;
    unsigned short* QKVb  = (unsigned short*)(ws);               // 96MB
    unsigned short* attnb = (unsigned short*)(ws + 100663296);   // 32MB
    unsigned short* Abuf  = (unsigned short*)(ws + 100663296);   // aliases attnb (pre-gemm1)
    unsigned short* Btqkv = (unsigned short*)(ws + 134217728);   // 3MB
    unsigned short* WoT   = (unsigned short*)(ws + 137363456);   // 2MB
    unsigned short* projb = (unsigned short*)(ws + 139460608);   // 32KB
    float*          KVg   = (float*)(ws + 139493376);            // 4MB
    float*          Ksumg = (float*)(ws + 143687680);            // 64KB
    unsigned short* KVTb  = (unsigned short*)(ws + 143753216);   // 2MB

    // fused: x -> out pass-through + x^T bf16 (x read once)
    trans_xcopy_kernel<<<dim3(64, 8, 4), 256, 0, stream>>>(x, out, Abuf);
    trans_qkv_kernel<<<dim3(16, 8, 3), 256, 0, stream>>>(Wq, Wk, Wv, Btqkv);
    trans_f2b_kernel<<<dim3(16, 16, 1), 256, 0, stream>>>(Wo, WoT, kE, kE, 0, 0);
    f2b_flat_kernel<<<dim3(16), 256, 0, stream>>>(proj, projb, kF * kD / 4);

    // GEMM1: M=16384 x N=3072, K=512 -> 128 x 12 = 1536 tiles of 128x256
    gemm128_b16<<<dim3(1536), 512, 0, stream>>>(Abuf, Btqkv, QKVb, kQKVs, kIn, 12);

    const int nz = kB * kH * kF * kD + kB * kH * kF;
    zero_kernel<<<dim3((nz + 255) / 256), 256, 0, stream>>>(KVg, nz);

    phaseA_mfma<<<dim3(64, 8), 256, 0, stream>>>(QKVb, projb, KVg, Ksumg);
    trans_f2b_kernel<<<dim3(1, 4, 64), 256, 0, stream>>>(KVg, KVTb, kF, kD,
                                                         (long)kF * kD, (long)kF * kD);
    phaseB_mfma<<<dim3(64, 8), 256, 0, stream>>>(QKVb, projb, KVTb, Ksumg, attnb);

    // GEMM2: M=16384 x N=1024, K=1024 -> 128 x 4 = 512 tiles of 128x256
    gemm128_out<<<dim3(512), 512, 0, stream>>>(attnb, WoT, out, kE, kE, 4);
}

// Round 8
// 355.408 us; speedup vs baseline: 1.0937x; 1.0135x over previous
//
#include <hip/hip_runtime.h>

// PerformerAttnBlock — Round 12: phaseA atomics -> disjoint partial stores
// (KVp 32MB in dead Abuf region) + kv_reduce fused sum-transpose; phaseA body
// reverted to serial staging (VGPR ~104, 3 blk/CU) keeping VT chunk-XOR swizzle.
// zero_kernel deleted. GEMMs/transposes/phaseB core unchanged (phaseB now sums
// 8 Ksum partials on load).
// B=4, IN=512, T=4096, EMBED=1024, H=16, D=64, F=256.
// WS (bytes):
//   0         QKVb bf16 [16384][3072] (96MB)
//   100663296 attnb bf16 [16384][1024] (32MB)
//             -- Abuf bf16 [16384][512] aliases pre-gemm1
//             -- KVp fp32 [8][64][256][64] aliases between gemm1 and phaseB (32MB exact)
//   134217728 Btqkv bf16 [3072][512] (3MB)
//   137363456 WoT bf16 [1024][1024] (2MB)
//   139460608 projb bf16 [256][64] (32KB)
//   139493376 Ksump fp32 [8][64][256] (512KB, old KVg slot)
//   143753216 KVTb bf16 [64][64][256] (2MB)

constexpr int kB  = 4;
constexpr int kIn = 512;
constexpr int kT  = 4096;
constexpr int kE  = 1024;
constexpr int kH  = 16;
constexpr int kD  = 64;
constexpr int kF  = 256;
constexpr int kQKVs = 3072;
constexpr int kNG  = 8;     // phaseA partial groups

typedef __attribute__((ext_vector_type(8))) short bf16x8;
typedef __attribute__((ext_vector_type(4))) float f32x4;

__device__ __forceinline__ unsigned short f2bf(float f) {
    unsigned u = __float_as_uint(f);
    u += 0x7fff + ((u >> 16) & 1);          // RNE
    return (unsigned short)(u >> 16);
}
__device__ __forceinline__ float bf2f(unsigned short s) {
    return __uint_as_float(((unsigned)s) << 16);
}
__device__ __forceinline__ void gload_lds16(const void* g, void* l) {
    __builtin_amdgcn_global_load_lds((const __attribute__((address_space(1))) void*)g,
                                     (__attribute__((address_space(3))) void*)l, 16, 0, 0);
}

// ---------------------------------------------------------------- flat fp32->bf16
__global__ __launch_bounds__(256) void f2b_flat_kernel(const float* __restrict__ s,
                                                       unsigned short* __restrict__ d, int n4) {
    int i = blockIdx.x * 256 + threadIdx.x;
    if (i < n4) {
        float4 v = ((const float4*)s)[i];
        ushort4 o;
        o.x = f2bf(v.x); o.y = f2bf(v.y); o.z = f2bf(v.z); o.w = f2bf(v.w);
        ((ushort4*)d)[i] = o;
    }
}

// ---------------------------------------------------------------- fused: x -> out copy + x^T bf16
__global__ __launch_bounds__(256) void trans_xcopy_kernel(const float* __restrict__ x,
                                                          float* __restrict__ out,
                                                          unsigned short* __restrict__ dst) {
    __shared__ float L[64][68];
    const int b = blockIdx.z;
    const float* src = x + (size_t)b * kIn * kT;
    float4* outb = (float4*)out + (size_t)b * ((kIn + kE) * kT / 4);
    unsigned short* dstb = dst + (size_t)b * kT * kIn;
    const int c0 = blockIdx.x * 64, r0 = blockIdx.y * 64;   // c over T, r over In
    const int tid = threadIdx.x;
#pragma unroll
    for (int it = 0; it < 4; ++it) {
        int lin = it * 256 + tid;
        int i = lin >> 4;
        int j4 = (lin & 15) * 4;
        float4 v = *(const float4*)(src + (size_t)(r0 + i) * kT + c0 + j4);
        outb[((size_t)(r0 + i) * kT + c0 + j4) >> 2] = v;   // pass-through copy
        L[j4 + 0][i] = v.x; L[j4 + 1][i] = v.y; L[j4 + 2][i] = v.z; L[j4 + 3][i] = v.w;
    }
    __syncthreads();
#pragma unroll
    for (int it = 0; it < 4; ++it) {
        int lin = it * 256 + tid;
        int cc = lin >> 4;
        int r4 = (lin & 15) * 4;
        ushort4 o;
        o.x = f2bf(L[cc][r4 + 0]); o.y = f2bf(L[cc][r4 + 1]);
        o.z = f2bf(L[cc][r4 + 2]); o.w = f2bf(L[cc][r4 + 3]);
        *(ushort4*)(dstb + (size_t)(c0 + cc) * kIn + r0 + r4) = o;
    }
}

// ---------------------------------------------------------------- transpose + fp32->bf16
__global__ __launch_bounds__(256) void trans_f2b_kernel(const float* __restrict__ src,
                                                        unsigned short* __restrict__ dst,
                                                        int R, int C,
                                                        long sstride, long dstride) {
    __shared__ float L[64][68];
    src += (size_t)blockIdx.z * sstride;
    dst += (size_t)blockIdx.z * dstride;
    const int c0 = blockIdx.x * 64, r0 = blockIdx.y * 64;
    const int tid = threadIdx.x;
#pragma unroll
    for (int it = 0; it < 4; ++it) {
        int lin = it * 256 + tid;
        int i = lin >> 4;
        int j4 = (lin & 15) * 4;
        float4 v = *(const float4*)(src + (size_t)(r0 + i) * C + c0 + j4);
        L[j4 + 0][i] = v.x; L[j4 + 1][i] = v.y; L[j4 + 2][i] = v.z; L[j4 + 3][i] = v.w;
    }
    __syncthreads();
#pragma unroll
    for (int it = 0; it < 4; ++it) {
        int lin = it * 256 + tid;
        int cc = lin >> 4;
        int r4 = (lin & 15) * 4;
        ushort4 o;
        o.x = f2bf(L[cc][r4 + 0]); o.y = f2bf(L[cc][r4 + 1]);
        o.z = f2bf(L[cc][r4 + 2]); o.w = f2bf(L[cc][r4 + 3]);
        *(ushort4*)(dst + (size_t)(c0 + cc) * R + r0 + r4) = o;
    }
}

// ---------------------------------------------------------------- fused Wq/Wk/Wv transpose
__global__ __launch_bounds__(256) void trans_qkv_kernel(const float* __restrict__ Wq,
                                                        const float* __restrict__ Wk,
                                                        const float* __restrict__ Wv,
                                                        unsigned short* __restrict__ dst) {
    __shared__ float L[64][68];
    const int z = blockIdx.z;
    const float* src = (z == 0) ? Wq : (z == 1) ? Wk : Wv;
    dst += (size_t)z * kE * kIn;
    const int c0 = blockIdx.x * 64, r0 = blockIdx.y * 64;   // c over E, r over In
    const int tid = threadIdx.x;
#pragma unroll
    for (int it = 0; it < 4; ++it) {
        int lin = it * 256 + tid;
        int i = lin >> 4;
        int j4 = (lin & 15) * 4;
        float4 v = *(const float4*)(src + (size_t)(r0 + i) * kE + c0 + j4);
        L[j4 + 0][i] = v.x; L[j4 + 1][i] = v.y; L[j4 + 2][i] = v.z; L[j4 + 3][i] = v.w;
    }
    __syncthreads();
#pragma unroll
    for (int it = 0; it < 4; ++it) {
        int lin = it * 256 + tid;
        int cc = lin >> 4;
        int r4 = (lin & 15) * 4;
        ushort4 o;
        o.x = f2bf(L[cc][r4 + 0]); o.y = f2bf(L[cc][r4 + 1]);
        o.z = f2bf(L[cc][r4 + 2]); o.w = f2bf(L[cc][r4 + 3]);
        *(ushort4*)(dst + (size_t)(c0 + cc) * kIn + r0 + r4) = o;
    }
}

// ---------------------------------------------------------------- kv_reduce: sum 8 partials + transpose + bf16
// KVp [g][bh][256 f][64 d] fp32 -> KVTb [bh][64 d][256 f] bf16. grid (4 ftile, 64 bh).
__global__ __launch_bounds__(256) void kv_reduce_kernel(const float* __restrict__ KVp,
                                                        unsigned short* __restrict__ KVTb) {
    __shared__ float L[64][68];
    const int r0 = blockIdx.x * 64;       // f tile
    const int bh = blockIdx.y;
    const int tid = threadIdx.x;
#pragma unroll
    for (int it = 0; it < 4; ++it) {
        int lin = it * 256 + tid;
        int i = lin >> 4;                 // f within tile
        int j4 = (lin & 15) * 4;          // d
        float4 s = {0.f, 0.f, 0.f, 0.f};
#pragma unroll
        for (int g = 0; g < kNG; ++g) {
            float4 v = *(const float4*)(KVp + ((size_t)(g * 64 + bh) * 256 + r0 + i) * 64 + j4);
            s.x += v.x; s.y += v.y; s.z += v.z; s.w += v.w;
        }
        L[j4 + 0][i] = s.x; L[j4 + 1][i] = s.y; L[j4 + 2][i] = s.z; L[j4 + 3][i] = s.w;
    }
    __syncthreads();
#pragma unroll
    for (int it = 0; it < 4; ++it) {
        int lin = it * 256 + tid;
        int cc = lin >> 4;                // d
        int r4 = (lin & 15) * 4;          // f within tile
        ushort4 o;
        o.x = f2bf(L[cc][r4 + 0]); o.y = f2bf(L[cc][r4 + 1]);
        o.z = f2bf(L[cc][r4 + 2]); o.w = f2bf(L[cc][r4 + 3]);
        *(ushort4*)(KVTb + (size_t)bh * 16384 + (size_t)cc * kF + r0 + r4) = o;
    }
}

// ================================================================ 128x256 BK=32 GEMM core
__device__ __forceinline__ void gemm128_mainloop(const unsigned short* __restrict__ A,
                                                 const unsigned short* __restrict__ Bt,
                                                 int K, int m0, int n0,
                                                 unsigned short* As, unsigned short* Bs,
                                                 f32x4 (&acc)[4][4]) {
    const int tid = threadIdx.x, lane = tid & 63, w = tid >> 6;
    const int col = lane & 15, quad = lane >> 4;
    const int wm = (w >> 2) * 64, wn = (w & 3) * 64;
    const int nt = K >> 5;

    const int srow = tid >> 2;
    const int schk = (tid & 3) ^ ((tid >> 3) & 3);
    const unsigned short* Agl  = A  + (size_t)(m0 + srow) * K + schk * 8;
    const unsigned short* Bgl0 = Bt + (size_t)(n0 + srow) * K + schk * 8;
    const unsigned short* Bgl1 = Bgl0 + (size_t)128 * K;
    unsigned short* Asw = As + w * 512;
    unsigned short* Bsw = Bs + w * 512;

    auto stage = [&](int kt, int buf) {
        gload_lds16(Agl  + kt * 32, Asw + buf * 4096);
        gload_lds16(Bgl0 + kt * 32, Bsw + buf * 8192);
        gload_lds16(Bgl1 + kt * 32, Bsw + buf * 8192 + 4096);
    };

#pragma unroll
    for (int i = 0; i < 4; ++i)
#pragma unroll
        for (int j = 0; j < 4; ++j) acc[i][j] = (f32x4){0.f, 0.f, 0.f, 0.f};

    stage(0, 0);
    if (nt > 1) stage(1, 1);
    asm volatile("s_waitcnt vmcnt(3)" ::: "memory");
    __builtin_amdgcn_s_barrier();
    __builtin_amdgcn_sched_barrier(0);

    const int rchk = (quad ^ ((col >> 1) & 3)) * 8;

    for (int t = 0; t < nt; ++t) {
        const int cur = t & 1;
        const unsigned short* Ab = As + cur * 4096;
        const unsigned short* Bb = Bs + cur * 8192;
        bf16x8 av[4], bv[4];
#pragma unroll
        for (int i = 0; i < 4; ++i)
            av[i] = *(const bf16x8*)&Ab[(wm + i * 16 + col) * 32 + rchk];
#pragma unroll
        for (int j = 0; j < 4; ++j)
            bv[j] = *(const bf16x8*)&Bb[(wn + j * 16 + col) * 32 + rchk];
        asm volatile("s_waitcnt lgkmcnt(0)" ::: "memory");
        __builtin_amdgcn_sched_barrier(0);
        __builtin_amdgcn_s_barrier();
        if (t + 2 < nt) stage(t + 2, cur);
        __builtin_amdgcn_sched_barrier(0);
#pragma unroll
        for (int i = 0; i < 4; ++i)
#pragma unroll
            for (int j = 0; j < 4; ++j)
                acc[i][j] = __builtin_amdgcn_mfma_f32_16x16x32_bf16(av[i], bv[j], acc[i][j], 0, 0, 0);
        if (t + 1 < nt) {
            __builtin_amdgcn_sched_barrier(0);
            if (t + 2 < nt) asm volatile("s_waitcnt vmcnt(3)" ::: "memory");
            else            asm volatile("s_waitcnt vmcnt(0)" ::: "memory");
            __builtin_amdgcn_sched_barrier(0);
            __builtin_amdgcn_s_barrier();
            __builtin_amdgcn_sched_barrier(0);
        }
    }
}

// ---------------------------------------------------------------- GEMM1: bf16 out
__global__ __launch_bounds__(512, 4) void gemm128_b16(const unsigned short* __restrict__ A,
                                                      const unsigned short* __restrict__ Bt,
                                                      unsigned short* __restrict__ C,
                                                      int N, int K, int ntN) {
    __shared__ unsigned short As[2 * 4096];
    __shared__ unsigned short Bs[2 * 8192];
    const int tid = threadIdx.x, lane = tid & 63, w = tid >> 6;
    const int col = lane & 15, quad = lane >> 4;
    const int wm = (w >> 2) * 64, wn = (w & 3) * 64;
    const int bid = blockIdx.x;
    const int qch = gridDim.x >> 3;
    const int swb = (bid & 7) * qch + (bid >> 3);
    const int mt = swb / ntN, ntl = swb - mt * ntN;
    const int m0 = mt * 128, n0 = ntl * 256;

    f32x4 acc[4][4];
    gemm128_mainloop(A, Bt, K, m0, n0, As, Bs, acc);

    float* Tw = (float*)As + w * 336;
    const int t2 = lane >> 2, n4 = (lane & 3) * 4;
#pragma unroll
    for (int ri = 0; ri < 4; ++ri)
#pragma unroll
        for (int cj = 0; cj < 4; ++cj) {
#pragma unroll
            for (int r = 0; r < 4; ++r)
                Tw[(quad * 4 + r) * 20 + col] = acc[ri][cj][r];
            float4 v = *(const float4*)&Tw[t2 * 20 + n4];
            ushort4 o;
            o.x = f2bf(v.x); o.y = f2bf(v.y); o.z = f2bf(v.z); o.w = f2bf(v.w);
            *(ushort4*)(C + (size_t)(m0 + wm + ri * 16 + t2) * N + n0 + wn + cj * 16 + n4) = o;
        }
}

// ---------------------------------------------------------------- GEMM2: attn @ Wo, fp32 transposed out
__global__ __launch_bounds__(512, 4) void gemm128_out(const unsigned short* __restrict__ A,
                                                      const unsigned short* __restrict__ Bt,
                                                      float* __restrict__ out,
                                                      int N, int K, int ntN) {
    __shared__ unsigned short As[2 * 4096];
    __shared__ unsigned short Bs[2 * 8192];
    const int tid = threadIdx.x, lane = tid & 63, w = tid >> 6;
    const int col = lane & 15, quad = lane >> 4;
    const int wm = (w >> 2) * 64, wn = (w & 3) * 64;
    const int bid = blockIdx.x;
    const int qch = gridDim.x >> 3;
    const int swb = (bid & 7) * qch + (bid >> 3);
    const int mt = swb / ntN, ntl = swb - mt * ntN;
    const int m0 = mt * 128, n0 = ntl * 256;

    f32x4 acc[4][4];
    gemm128_mainloop(A, Bt, K, m0, n0, As, Bs, acc);

    const int b = m0 >> 12, t0 = m0 & 4095;
    float* dst = out + (size_t)b * (kIn + kE) * kT + (size_t)kIn * kT;
    float* Tw = (float*)As + w * 336;
    const int n2 = lane >> 2, t4 = (lane & 3) * 4;
#pragma unroll
    for (int ri = 0; ri < 4; ++ri)
#pragma unroll
        for (int cj = 0; cj < 4; ++cj) {
            *(float4*)&Tw[col * 20 + quad * 4] =
                (float4){acc[ri][cj][0], acc[ri][cj][1], acc[ri][cj][2], acc[ri][cj][3]};
            float4 v = *(const float4*)&Tw[n2 * 20 + t4];
            *(float4*)(dst + (size_t)(n0 + wn + cj * 16 + n2) * kT + t0 + wm + ri * 16 + t4) = v;
        }
}

// ---------------------------------------------------------------- Phase A (MFMA): KV, Ksum partials
// grid (64 bh, 8 grp). Serial staging (3 blocks/CU); VT chunk-XOR swizzled;
// partial results plain-stored to KVp/Ksump (no atomics, no zero-init).
__global__ __launch_bounds__(256) void phaseA_mfma(const unsigned short* __restrict__ QKVb,
                                                   const unsigned short* __restrict__ projb,
                                                   float* __restrict__ KVp,
                                                   float* __restrict__ Ksump) {
    __shared__ unsigned short Ks[64 * 64];     // [t][d] XOR-swizzled chunks
    __shared__ unsigned short VT[64 * 72];     // [d][t], chunk-XOR swizzled
    __shared__ unsigned short KpT[256 * 72];   // [f][t] (per-wave rows)
    const int tid = threadIdx.x, lane = tid & 63, w = tid >> 6;
    const int col = lane & 15, quad = lane >> 4;
    const int bh = blockIdx.x, b = bh >> 4, h = bh & 15;
    const int grp = blockIdx.y;
    const int f0 = w * 64;
    const int swz = col & 7;

    const int vt_t = tid >> 4, vd4 = (tid & 15) * 4;
    const int vsw = (vd4 >> 2) & 7;

    bf16x8 bB[2][4];   // proj B-fragments, invariant
#pragma unroll
    for (int s = 0; s < 2; ++s)
#pragma unroll
        for (int j = 0; j < 4; ++j)
            bB[s][j] = *(const bf16x8*)(projb + (size_t)(f0 + j * 16 + col) * 64 + s * 32 + quad * 8);

    f32x4 kvacc[4][4];
#pragma unroll
    for (int i = 0; i < 4; ++i)
#pragma unroll
        for (int j = 0; j < 4; ++j) kvacc[i][j] = (f32x4){0.f, 0.f, 0.f, 0.f};
    float ksum_acc[4] = {0.f, 0.f, 0.f, 0.f};

    for (int it = 0; it < 8; ++it) {
        const size_t rowbase = (size_t)(b * kT + grp * 512 + it * 64) * kQKVs + h * kD;
        __syncthreads();
        // K staging: gload_lds (pre-swizzled global source, linear LDS dest)
#pragma unroll
        for (int i2 = 0; i2 < 2; ++i2) {
            int p = (i2 * 4 + w) * 64 + lane;
            int row = p >> 3;
            int cg = ((p & 7) ^ (row & 7)) * 8;
            gload_lds16(QKVb + rowbase + 1024 + (size_t)row * kQKVs + cg, &Ks[(i2 * 4 + w) * 512]);
        }
        // V staging: reg load + chunk-XOR-swizzled transpose write
        ushort4 vr[4];
#pragma unroll
        for (int r = 0; r < 4; ++r)
            vr[r] = *(const ushort4*)(QKVb + rowbase + 2048 + (size_t)(r * 16 + vt_t) * kQKVs + vd4);
#pragma unroll
        for (int r = 0; r < 4; ++r) {
            const int t = r * 16 + vt_t;
            const int bo = (((t >> 3) ^ vsw) * 8) + (t & 7);
            VT[(vd4 + 0) * 72 + bo] = vr[r].x;
            VT[(vd4 + 1) * 72 + bo] = vr[r].y;
            VT[(vd4 + 2) * 72 + bo] = vr[r].z;
            VT[(vd4 + 3) * 72 + bo] = vr[r].w;
        }
        __syncthreads();
        // proj MFMA: sa = K @ proj^T, then exp -> KpT
        bf16x8 av[2][4];
#pragma unroll
        for (int s = 0; s < 2; ++s)
#pragma unroll
            for (int i = 0; i < 4; ++i)
                av[s][i] = *(const bf16x8*)&Ks[(i * 16 + col) * 64 + ((s * 4 + quad) ^ swz) * 8];
#pragma unroll
        for (int j = 0; j < 4; ++j) {
            f32x4 sa[4];
#pragma unroll
            for (int i = 0; i < 4; ++i) sa[i] = (f32x4){0.f, 0.f, 0.f, 0.f};
#pragma unroll
            for (int s = 0; s < 2; ++s)
#pragma unroll
                for (int i = 0; i < 4; ++i)
                    sa[i] = __builtin_amdgcn_mfma_f32_16x16x32_bf16(av[s][i], bB[s][j], sa[i], 0, 0, 0);
            const int f = f0 + j * 16 + col;
#pragma unroll
            for (int i = 0; i < 4; ++i) {
                float e0 = __expf(sa[i][0]) + 1e-6f;
                float e1 = __expf(sa[i][1]) + 1e-6f;
                float e2 = __expf(sa[i][2]) + 1e-6f;
                float e3 = __expf(sa[i][3]) + 1e-6f;
                ksum_acc[j] += (e0 + e1) + (e2 + e3);
                ushort4 pk;
                pk.x = f2bf(e0); pk.y = f2bf(e1); pk.z = f2bf(e2); pk.w = f2bf(e3);
                *(ushort4*)&KpT[f * 72 + i * 16 + quad * 4] = pk;
            }
        }
        // KV MFMA: kvacc += Kp^T @ V (VT swizzled read)
#pragma unroll
        for (int s = 0; s < 2; ++s) {
            const int kc = s * 32 + quad * 8;
            bf16x8 a2[4], b2[4];
#pragma unroll
            for (int i = 0; i < 4; ++i)
                a2[i] = *(const bf16x8*)&KpT[(f0 + i * 16 + col) * 72 + kc];
#pragma unroll
            for (int jn = 0; jn < 4; ++jn) {
                const int d = jn * 16 + col;
                b2[jn] = *(const bf16x8*)&VT[d * 72 + (((s * 4 + quad) ^ ((d >> 2) & 7)) * 8)];
            }
#pragma unroll
            for (int i = 0; i < 4; ++i)
#pragma unroll
                for (int jn = 0; jn < 4; ++jn)
                    kvacc[i][jn] = __builtin_amdgcn_mfma_f32_16x16x32_bf16(a2[i], b2[jn], kvacc[i][jn], 0, 0, 0);
        }
    }
    // disjoint partial stores (no atomics)
    float* dst = KVp + (size_t)(grp * 64 + bh) * 16384;
#pragma unroll
    for (int i = 0; i < 4; ++i)
#pragma unroll
        for (int jn = 0; jn < 4; ++jn)
#pragma unroll
            for (int r = 0; r < 4; ++r)
                dst[(size_t)(f0 + i * 16 + quad * 4 + r) * kD + jn * 16 + col] = kvacc[i][jn][r];
#pragma unroll
    for (int j = 0; j < 4; ++j) {
        float v = ksum_acc[j];
        v += __shfl_xor(v, 16);
        v += __shfl_xor(v, 32);
        if (quad == 0) Ksump[(size_t)(grp * 64 + bh) * kF + f0 + j * 16 + col] = v;
    }
}

// ---------------------------------------------------------------- Phase B (MFMA): attn bf16
__global__ __launch_bounds__(256) void phaseB_mfma(const unsigned short* __restrict__ QKVb,
                                                   const unsigned short* __restrict__ projb,
                                                   const unsigned short* __restrict__ KVTb,
                                                   const float* __restrict__ Ksump,
                                                   unsigned short* __restrict__ attnb) {
    __shared__ unsigned short Qs[64 * 64];      // [t][d] XOR-swizzled chunks
    __shared__ unsigned short Qp[64 * 264];     // [t][f] pad 8
    __shared__ unsigned short KVTs[64 * 264];   // [d][f] pad 8
    __shared__ float KsS[256];
    __shared__ float denp[4][64];
    const int tid = threadIdx.x, lane = tid & 63, w = tid >> 6;
    const int col = lane & 15, quad = lane >> 4;
    const int bh = blockIdx.x, b = bh >> 4, h = bh & 15;
    const int grp = blockIdx.y;
    const int f0 = w * 64;
    const int swz = col & 7;

    bf16x8 bB[2][4];
#pragma unroll
    for (int s = 0; s < 2; ++s)
#pragma unroll
        for (int j = 0; j < 4; ++j)
            bB[s][j] = *(const bf16x8*)(projb + (size_t)(f0 + j * 16 + col) * 64 + s * 32 + quad * 8);

#pragma unroll
    for (int r = 0; r < 8; ++r) {
        int lin = r * 256 + tid;
        int d = lin >> 5, fc8 = (lin & 31) * 8;
        *(bf16x8*)&KVTs[d * 264 + fc8] = *(const bf16x8*)(KVTb + (size_t)bh * 16384 + d * 256 + fc8);
    }
    {
        float s = 0.f;
#pragma unroll
        for (int g = 0; g < kNG; ++g)
            s += Ksump[(size_t)(g * 64 + bh) * kF + tid];
        KsS[tid] = s;
    }

    for (int it = 0; it < 8; ++it) {
        const int tg0 = grp * 512 + it * 64;
        const size_t rowbase = (size_t)(b * kT + tg0) * kQKVs + h * kD;
        __syncthreads();
#pragma unroll
        for (int i2 = 0; i2 < 2; ++i2) {
            int p = (i2 * 4 + w) * 64 + lane;
            int row = p >> 3;
            int cg = ((p & 7) ^ (row & 7)) * 8;
            gload_lds16(QKVb + rowbase + (size_t)row * kQKVs + cg, &Qs[(i2 * 4 + w) * 512]);
        }
        __syncthreads();
        bf16x8 av[2][4];
#pragma unroll
        for (int s = 0; s < 2; ++s)
#pragma unroll
            for (int i = 0; i < 4; ++i)
                av[s][i] = *(const bf16x8*)&Qs[(i * 16 + col) * 64 + ((s * 4 + quad) ^ swz) * 8];
#pragma unroll
        for (int j = 0; j < 4; ++j) {
            f32x4 sa[4];
#pragma unroll
            for (int i = 0; i < 4; ++i) sa[i] = (f32x4){0.f, 0.f, 0.f, 0.f};
#pragma unroll
            for (int s = 0; s < 2; ++s)
#pragma unroll
                for (int i = 0; i < 4; ++i)
                    sa[i] = __builtin_amdgcn_mfma_f32_16x16x32_bf16(av[s][i], bB[s][j], sa[i], 0, 0, 0);
            const int f = f0 + j * 16 + col;
#pragma unroll
            for (int i = 0; i < 4; ++i) {
                const int tb = i * 16 + quad * 4;
                Qp[(tb + 0) * 264 + f] = f2bf(__expf(sa[i][0]) + 1e-6f);
                Qp[(tb + 1) * 264 + f] = f2bf(__expf(sa[i][1]) + 1e-6f);
                Qp[(tb + 2) * 264 + f] = f2bf(__expf(sa[i][2]) + 1e-6f);
                Qp[(tb + 3) * 264 + f] = f2bf(__expf(sa[i][3]) + 1e-6f);
            }
        }
        float dp = 0.f;
#pragma unroll
        for (int u = 0; u < 64; u += 8) {
            bf16x8 qv = *(const bf16x8*)&Qp[lane * 264 + f0 + u];
#pragma unroll
            for (int k2 = 0; k2 < 8; ++k2)
                dp += bf2f((unsigned short)qv[k2]) * KsS[f0 + u + k2];
        }
        denp[w][lane] = dp;
        __syncthreads();
        f32x4 nacc[4];
#pragma unroll
        for (int jn = 0; jn < 4; ++jn) nacc[jn] = (f32x4){0.f, 0.f, 0.f, 0.f};
#pragma unroll
        for (int s = 0; s < 8; ++s) {
            const int kc = s * 32 + quad * 8;
            bf16x8 aq = *(const bf16x8*)&Qp[(w * 16 + col) * 264 + kc];
#pragma unroll
            for (int jn = 0; jn < 4; ++jn) {
                bf16x8 bk = *(const bf16x8*)&KVTs[(jn * 16 + col) * 264 + kc];
                nacc[jn] = __builtin_amdgcn_mfma_f32_16x16x32_bf16(aq, bk, nacc[jn], 0, 0, 0);
            }
        }
#pragma unroll
        for (int r = 0; r < 4; ++r) {
            const int tl = w * 16 + quad * 4 + r;
            float den = denp[0][tl] + denp[1][tl] + denp[2][tl] + denp[3][tl];
            float rd = 1.f / fmaxf(den, 1e-6f);
            const size_t ob = (size_t)(b * kT + tg0 + tl) * kE + h * kD;
#pragma unroll
            for (int jn = 0; jn < 4; ++jn)
                attnb[ob + jn * 16 + col] = f2bf(nacc[jn][r] * rd);
        }
    }
}

// ---------------------------------------------------------------- launch
extern "C" void kernel_launch(void* const* d_in, const int* in_sizes, int n_in,
                              void* d_out, int out_size, void* d_ws, size_t ws_size,
                              hipStream_t stream) {
    (void)in_sizes; (void)n_in; (void)out_size; (void)ws_size;
    const float* x    = (const float*)d_in[0];
    const float* Wq   = (const float*)d_in[1];
    const float* Wk   = (const float*)d_in[2];
    const float* Wv   = (const float*)d_in[3];
    const float* Wo   = (const float*)d_in[4];
    const float* proj = (const float*)d_in[5];
    float* out = (float*)d_out;

    char* ws = (char*)d_ws;
    unsigned short* QKVb  = (unsigned short*)(ws);               // 96MB
    unsigned short* attnb = (unsigned short*)(ws + 100663296);   // 32MB
    unsigned short* Abuf  = (unsigned short*)(ws + 100663296);   // aliases attnb (pre-gemm1)
    float*          KVp   = (float*)(ws + 100663296);            // aliases attnb (gemm1..phaseB window), 32MB exact
    unsigned short* Btqkv = (unsigned short*)(ws + 134217728);   // 3MB
    unsigned short* WoT   = (unsigned short*)(ws + 137363456);   // 2MB
    unsigned short* projb = (unsigned short*)(ws + 139460608);   // 32KB
    float*          Ksump = (float*)(ws + 139493376);            // 512KB (old KVg slot)
    unsigned short* KVTb  = (unsigned short*)(ws + 143753216);   // 2MB

    // fused: x -> out pass-through + x^T bf16 (x read once)
    trans_xcopy_kernel<<<dim3(64, 8, 4), 256, 0, stream>>>(x, out, Abuf);
    trans_qkv_kernel<<<dim3(16, 8, 3), 256, 0, stream>>>(Wq, Wk, Wv, Btqkv);
    trans_f2b_kernel<<<dim3(16, 16, 1), 256, 0, stream>>>(Wo, WoT, kE, kE, 0, 0);
    f2b_flat_kernel<<<dim3(16), 256, 0, stream>>>(proj, projb, kF * kD / 4);

    // GEMM1: M=16384 x N=3072, K=512 -> 128 x 12 = 1536 tiles of 128x256
    gemm128_b16<<<dim3(1536), 512, 0, stream>>>(Abuf, Btqkv, QKVb, kQKVs, kIn, 12);

    // Phase A: partial KV/Ksum per (bh, grp) — no atomics, no zero-init
    phaseA_mfma<<<dim3(64, kNG), 256, 0, stream>>>(QKVb, projb, KVp, Ksump);
    // reduce partials + transpose -> KVTb
    kv_reduce_kernel<<<dim3(4, 64), 256, 0, stream>>>(KVp, KVTb);
    phaseB_mfma<<<dim3(64, 8), 256, 0, stream>>>(QKVb, projb, KVTb, Ksump, attnb);

    // GEMM2: M=16384 x N=1024, K=1024 -> 128 x 4 = 512 tiles of 128x256
    gemm128_out<<<dim3(512), 512, 0, stream>>>(attnb, WoT, out, kE, kE, 4);
}